// Round 10
// baseline (2591.338 us; speedup 1.0000x reference)
//
#include <hip/hip_runtime.h>
#include <hip/hip_bf16.h>
#include <math.h>

// NeighborGatedAttention, bf16-MFMA, DUAL-b + deep-ILP version.
// L=2, B=8192, NNEI=128, EMB=HID=128. One block (512 thr = 8 waves) handles
// TWO b's. vs R9: (1) S phase b0/b1 INTERLEAVED (2 MFMA chains in flight),
// (2) PV MFMAs b0/b1 INTERLEAVED (oacc0+oacc1 live), (3) explicit next-iter
// weight prefetch in q/k/v and VW loops (L2 latency overlaps current tile).
// Register budget: 2 waves/SIMD -> 256 total; est peak ~190 (R9 used 120+acc).
// LDS 154.6KB: per b bufA (q->v->VW^T) + bufB (k->P) + tables. 1 block/CU.
// All GEMMs v_mfma_f32_16x16x32_bf16; l2-norms from fp32 accs; softmax/LN fp32.

typedef __attribute__((ext_vector_type(8))) short bf16x8; // 8 bf16 = 4 VGPR
typedef __attribute__((ext_vector_type(4))) float f32x4;
typedef unsigned short ushort_t;

constexpr float F_SHIFT   = 20.0f;
constexpr float F_SCALING = 0.08838834764831845f; // 128^-0.5
constexpr float F_LNEPS   = 1e-5f;

constexpr int ROWP = 136;                 // ushort row pitch (272B)
constexpr int BUF_US = 128 * ROWP;        // 17408 ushorts per buffer
constexpr size_t WTI_ELEMS = 2 * 384 * 128;
constexpr size_t WTO_ELEMS = 2 * 128 * 128;
constexpr int TAB_F = 1920;               // per-b table floats
constexpr int LDS_BYTES = 4 * BUF_US * 2 + 2 * TAB_F * 4; // 154624

#define MFMA(a, b, c) __builtin_amdgcn_mfma_f32_16x16x32_bf16(a, b, c, 0, 0, 0)

__device__ __forceinline__ ushort_t f2bf(float f) {
  __hip_bfloat16 h = __float2bfloat16(f);
  return *reinterpret_cast<ushort_t*>(&h);
}
__device__ __forceinline__ ushort4 pack4(float a, float b, float c, float d) {
  return make_ushort4(f2bf(a), f2bf(b), f2bf(c), f2bf(d));
}

// A/B fragment from pre-transposed bf16 weights (WS) or fp32 gather fallback.
template <bool WS>
__device__ __forceinline__ bf16x8 wt_frag(const ushort_t* __restrict__ wt,
                                          const float* __restrict__ W,
                                          int r, int c, int ldW) {
  if constexpr (WS) {
    return *(const bf16x8*)(wt + r * 128 + c);
  } else {
    bf16x8 f;
#pragma unroll
    for (int j = 0; j < 8; ++j) f[j] = (short)f2bf(W[(size_t)(c + j) * ldW + r]);
    return f;
  }
}

__global__ void prep_weights(const float* __restrict__ Win, const float* __restrict__ Wout,
                             ushort_t* __restrict__ wtI, ushort_t* __restrict__ wtO) {
  const int i = blockIdx.x * 256 + threadIdx.x;
  if (i < (int)WTI_ELEMS) {   // wtI[l][h][e] = bf16(Win[l][e][h])
    const int l = i / (384 * 128), r = i % (384 * 128), h = r >> 7, e = r & 127;
    wtI[i] = f2bf(Win[l * (128 * 384) + e * 384 + h]);
  }
  if (i < (int)WTO_ELEMS) {   // wtO[l][e][h] = bf16(Wout[l][h][e])
    const int l = i >> 14, r = i & 16383, e = r >> 7, h = r & 127;
    wtO[i] = f2bf(Wout[(l << 14) + h * 128 + e]);
  }
}

__device__ __forceinline__ bf16x8 load_xf(const float* xr) {
  const float4 a = *(const float4*)xr;
  const float4 c = *(const float4*)(xr + 4);
  bf16x8 f;
  f[0] = (short)f2bf(a.x); f[1] = (short)f2bf(a.y);
  f[2] = (short)f2bf(a.z); f[3] = (short)f2bf(a.w);
  f[4] = (short)f2bf(c.x); f[5] = (short)f2bf(c.y);
  f[6] = (short)f2bf(c.z); f[7] = (short)f2bf(c.w);
  return f;
}

template <bool WS>
__global__ __launch_bounds__(512, 2)
void ngatt_dual(const float* __restrict__ G, const int* __restrict__ nmask,
                const float* __restrict__ r3, const float* __restrict__ swg,
                const float* __restrict__ Win, const float* __restrict__ bin,
                const float* __restrict__ Wout, const float* __restrict__ bout,
                const float* __restrict__ lng, const float* __restrict__ lnb,
                const ushort_t* __restrict__ wtin, const ushort_t* __restrict__ wtout,
                float* __restrict__ xout) {
  extern __shared__ char smem[];
  ushort_t* bufA0 = (ushort_t*)smem;           // b0: q -> v -> VW^T
  ushort_t* bufB0 = bufA0 + BUF_US;            // b0: k -> P
  ushort_t* bufA1 = bufB0 + BUF_US;            // b1: q -> v -> VW^T
  ushort_t* bufB1 = bufA1 + BUF_US;            // b1: k -> P
  float* tab0 = (float*)(bufB1 + BUF_US);
  float* tab1 = tab0 + TAB_F;
  // per-b table layout (float offsets):
  //   pQ 0, pK 128, pV 256, sIV 384, fA 512..1023, fB 1024..1279,
  //   sSW 1280, sMK 1408, sRX 1536, sRY 1664, sRZ 1792

  const int bid = blockIdx.x, t = threadIdx.x;
  const int w = t >> 6, l = t & 63, lc = l & 15, lg = l >> 4;
  const int b0 = 2 * bid, b1 = b0 + 1;
  const size_t bb0 = (size_t)b0 * (128 * 128);
  const size_t bb1 = (size_t)b1 * (128 * 128);
  const int n_mine = 16 * w + lc;

  if (t < 256) {
    const int tb = t >> 7, tt = t & 127;
    float* T = tb ? tab1 : tab0;
    const size_t gi = (size_t)(b0 + tb) * 128 + tt;
    T[1280 + tt] = swg[gi];
    T[1408 + tt] = nmask[gi] ? 1.0f : 0.0f;
    T[1536 + tt] = r3[gi * 3 + 0];
    T[1664 + tt] = r3[gi * 3 + 1];
    T[1792 + tt] = r3[gi * 3 + 2];
  }
  __syncthreads();

  for (int layer = 0; layer < 2; ++layer) {
    const float* xsrc0 = layer ? (xout + bb0) : (G + bb0);
    const float* xsrc1 = layer ? (xout + bb1) : (G + bb1);
    const ushort_t* wtI = wtin + (size_t)layer * 384 * 128;
    const ushort_t* wtO = wtout + (size_t)layer * 128 * 128;
    const float* WinL  = Win  + (size_t)layer * 128 * 384;
    const float* WoutL = Wout + (size_t)layer * 128 * 128;
    const float* binL  = bin  + layer * 384;
    const float* boutL = bout + layer * 128;
    const float* lngL  = lng  + layer * 128;
    const float* lnbL  = lnb  + layer * 128;

    // ---- hoist x B-fragments for both b's (col n_mine) ----
    bf16x8 xf0[4], xf1[4];
#pragma unroll
    for (int kk = 0; kk < 4; ++kk) {
      xf0[kk] = load_xf(xsrc0 + (size_t)n_mine * 128 + 8 * lg + 32 * kk);
      xf1[kk] = load_xf(xsrc1 + (size_t)n_mine * 128 + 8 * lg + 32 * kk);
    }

    // ---- q: tiles 0..7 -> bufA0/bufA1 (weights shared; explicit prefetch) ----
    float ssq0 = 0.f, ssq1 = 0.f, ssk0 = 0.f, ssk1 = 0.f;
    {
      bf16x8 aw[4], nw[4];
#pragma unroll
      for (int kk = 0; kk < 4; ++kk)
        aw[kk] = wt_frag<WS>(wtI, WinL, lc, 8 * lg + 32 * kk, 384);
#pragma unroll 1
      for (int i = 0; i < 8; ++i) {
        if (i < 7) {
#pragma unroll
          for (int kk = 0; kk < 4; ++kk)
            nw[kk] = wt_frag<WS>(wtI, WinL, 16 * (i + 1) + lc, 8 * lg + 32 * kk, 384);
        }
        f32x4 a0 = {0, 0, 0, 0}, a1 = {0, 0, 0, 0};
#pragma unroll
        for (int kk = 0; kk < 4; ++kk) {
          a0 = MFMA(aw[kk], xf0[kk], a0);
          a1 = MFMA(aw[kk], xf1[kk], a1);
        }
        const float4 bi = *(const float4*)&binL[16 * i + 4 * lg];
        {
          const float v0 = a0[0] + bi.x, v1 = a0[1] + bi.y, v2 = a0[2] + bi.z, v3 = a0[3] + bi.w;
          ssq0 += v0 * v0 + v1 * v1 + v2 * v2 + v3 * v3;
          *(ushort4*)(bufA0 + n_mine * ROWP + 16 * i + 4 * lg) = pack4(v0, v1, v2, v3);
        }
        {
          const float v0 = a1[0] + bi.x, v1 = a1[1] + bi.y, v2 = a1[2] + bi.z, v3 = a1[3] + bi.w;
          ssq1 += v0 * v0 + v1 * v1 + v2 * v2 + v3 * v3;
          *(ushort4*)(bufA1 + n_mine * ROWP + 16 * i + 4 * lg) = pack4(v0, v1, v2, v3);
        }
#pragma unroll
        for (int kk = 0; kk < 4; ++kk) aw[kk] = nw[kk];
      }
    }
    // ---- k: tiles 8..15 -> bufB0/bufB1 (prefetched) ----
    {
      bf16x8 aw[4], nw[4];
#pragma unroll
      for (int kk = 0; kk < 4; ++kk)
        aw[kk] = wt_frag<WS>(wtI, WinL, 128 + lc, 8 * lg + 32 * kk, 384);
#pragma unroll 1
      for (int i = 0; i < 8; ++i) {
        if (i < 7) {
#pragma unroll
          for (int kk = 0; kk < 4; ++kk)
            nw[kk] = wt_frag<WS>(wtI, WinL, 128 + 16 * (i + 1) + lc, 8 * lg + 32 * kk, 384);
        }
        f32x4 a0 = {0, 0, 0, 0}, a1 = {0, 0, 0, 0};
#pragma unroll
        for (int kk = 0; kk < 4; ++kk) {
          a0 = MFMA(aw[kk], xf0[kk], a0);
          a1 = MFMA(aw[kk], xf1[kk], a1);
        }
        const float4 bi = *(const float4*)&binL[128 + 16 * i + 4 * lg];
        {
          const float v0 = a0[0] + bi.x, v1 = a0[1] + bi.y, v2 = a0[2] + bi.z, v3 = a0[3] + bi.w;
          ssk0 += v0 * v0 + v1 * v1 + v2 * v2 + v3 * v3;
          *(ushort4*)(bufB0 + n_mine * ROWP + 16 * i + 4 * lg) = pack4(v0, v1, v2, v3);
        }
        {
          const float v0 = a1[0] + bi.x, v1 = a1[1] + bi.y, v2 = a1[2] + bi.z, v3 = a1[3] + bi.w;
          ssk1 += v0 * v0 + v1 * v1 + v2 * v2 + v3 * v3;
          *(ushort4*)(bufB1 + n_mine * ROWP + 16 * i + 4 * lg) = pack4(v0, v1, v2, v3);
        }
#pragma unroll
        for (int kk = 0; kk < 4; ++kk) aw[kk] = nw[kk];
      }
    }
    ssq0 += __shfl_xor(ssq0, 16); ssq0 += __shfl_xor(ssq0, 32);
    ssq1 += __shfl_xor(ssq1, 16); ssq1 += __shfl_xor(ssq1, 32);
    ssk0 += __shfl_xor(ssk0, 16); ssk0 += __shfl_xor(ssk0, 32);
    ssk1 += __shfl_xor(ssk1, 16); ssk1 += __shfl_xor(ssk1, 32);
    if (l < 16) {
      tab0[0 + n_mine] = ssq0; tab0[128 + n_mine] = ssk0;
      tab1[0 + n_mine] = ssq1; tab1[128 + n_mine] = ssk1;
    }
    __syncthreads();   // B1: q,k complete + norm partials

    if (t < 256) {
      const int tb = t >> 7, tt = t & 127;
      float* T = tb ? tab1 : tab0;
      T[0 + tt] = 1.0f / fmaxf(sqrtf(T[0 + tt]), 1e-12f);                 // 1/|q|
      T[512 + 4 * tt + 0] = (1.0f / fmaxf(sqrtf(T[128 + tt]), 1e-12f)) * F_SCALING;
      T[512 + 4 * tt + 1] = T[1280 + tt];   // sw
      T[512 + 4 * tt + 2] = 0.0f;
      T[512 + 4 * tt + 3] = T[1536 + tt];   // rx
      T[1024 + 2 * tt + 0] = T[1664 + tt];  // ry
      T[1024 + 2 * tt + 1] = T[1792 + tt];  // rz
    }
    // hoist q fragments for both b's (own rows)
    bf16x8 qf0[4], qf1[4];
#pragma unroll
    for (int kk = 0; kk < 4; ++kk) {
      qf0[kk] = *(const bf16x8*)(bufA0 + n_mine * ROWP + 8 * lg + 32 * kk);
      qf1[kk] = *(const bf16x8*)(bufA1 + n_mine * ROWP + 8 * lg + 32 * kk);
    }
    __syncthreads();   // B2: qf hoisted; factor tables ready; bufA free

    // ---- v: tiles 16..23 -> bufA0/bufA1 (weights shared; prefetched) ----
    float ssv0 = 0.f, ssv1 = 0.f;
    {
      bf16x8 aw[4], nw[4];
#pragma unroll
      for (int kk = 0; kk < 4; ++kk)
        aw[kk] = wt_frag<WS>(wtI, WinL, 256 + lc, 8 * lg + 32 * kk, 384);
#pragma unroll 1
      for (int i = 0; i < 8; ++i) {
        if (i < 7) {
#pragma unroll
          for (int kk = 0; kk < 4; ++kk)
            nw[kk] = wt_frag<WS>(wtI, WinL, 256 + 16 * (i + 1) + lc, 8 * lg + 32 * kk, 384);
        }
        f32x4 a0 = {0, 0, 0, 0}, a1 = {0, 0, 0, 0};
#pragma unroll
        for (int kk = 0; kk < 4; ++kk) {
          a0 = MFMA(aw[kk], xf0[kk], a0);
          a1 = MFMA(aw[kk], xf1[kk], a1);
        }
        const float4 bi = *(const float4*)&binL[256 + 16 * i + 4 * lg];
        {
          const float v0 = a0[0] + bi.x, v1 = a0[1] + bi.y, v2 = a0[2] + bi.z, v3 = a0[3] + bi.w;
          ssv0 += v0 * v0 + v1 * v1 + v2 * v2 + v3 * v3;
          *(ushort4*)(bufA0 + n_mine * ROWP + 16 * i + 4 * lg) = pack4(v0, v1, v2, v3);
        }
        {
          const float v0 = a1[0] + bi.x, v1 = a1[1] + bi.y, v2 = a1[2] + bi.z, v3 = a1[3] + bi.w;
          ssv1 += v0 * v0 + v1 * v1 + v2 * v2 + v3 * v3;
          *(ushort4*)(bufA1 + n_mine * ROWP + 16 * i + 4 * lg) = pack4(v0, v1, v2, v3);
        }
#pragma unroll
        for (int kk = 0; kk < 4; ++kk) aw[kk] = nw[kk];
      }
    }
    ssv0 += __shfl_xor(ssv0, 16); ssv0 += __shfl_xor(ssv0, 32);
    ssv1 += __shfl_xor(ssv1, 16); ssv1 += __shfl_xor(ssv1, 32);
    if (l < 16) { tab0[256 + n_mine] = ssv0; tab1[256 + n_mine] = ssv1; }

    // ---- S + softmax, b0/b1 INTERLEAVED (2 MFMA chains + 2 LDS streams) ----
    f32x4 sacc0[8], sacc1[8];
    float fac0, fac1;
    {
      const float iqn0 = tab0[0 + n_mine], iqn1 = tab1[0 + n_mine];
      const float swn0 = tab0[1280 + n_mine], swn1 = tab1[1280 + n_mine];
      const float rxn0 = tab0[1536 + n_mine], ryn0 = tab0[1664 + n_mine], rzn0 = tab0[1792 + n_mine];
      const float rxn1 = tab1[1536 + n_mine], ryn1 = tab1[1664 + n_mine], rzn1 = tab1[1792 + n_mine];
      float sum0 = 0.0f, sum1 = 0.0f;
#pragma unroll 2
      for (int mt = 0; mt < 8; ++mt) {
        bf16x8 kf0[4], kf1[4];
#pragma unroll
        for (int kk = 0; kk < 4; ++kk) {
          kf0[kk] = *(const bf16x8*)(bufB0 + (16 * mt + lc) * ROWP + 8 * lg + 32 * kk);
          kf1[kk] = *(const bf16x8*)(bufB1 + (16 * mt + lc) * ROWP + 8 * lg + 32 * kk);
        }
        f32x4 a0 = {0, 0, 0, 0}, a1 = {0, 0, 0, 0};
#pragma unroll
        for (int kk = 0; kk < 4; ++kk) {
          a0 = MFMA(kf0[kk], qf0[kk], a0);
          a1 = MFMA(kf1[kk], qf1[kk], a1);
        }
#pragma unroll
        for (int r2 = 0; r2 < 4; ++r2) {
          const int m = 16 * mt + 4 * lg + r2;
          {
            const float4 a4 = *(const float4*)&tab0[512 + 4 * m];
            const float2 b2 = *(const float2*)&tab0[1024 + 2 * m];
            const float sws = swn0 * a4.y;
            const float e = __expf((a0[r2] * iqn0 * a4.x + F_SHIFT) * sws - F_SHIFT);
            sum0 += e;
            a0[r2] = e * sws * (rxn0 * a4.w + ryn0 * b2.x + rzn0 * b2.y);
          }
          {
            const float4 a4 = *(const float4*)&tab1[512 + 4 * m];
            const float2 b2 = *(const float2*)&tab1[1024 + 2 * m];
            const float sws = swn1 * a4.y;
            const float e = __expf((a1[r2] * iqn1 * a4.x + F_SHIFT) * sws - F_SHIFT);
            sum1 += e;
            a1[r2] = e * sws * (rxn1 * a4.w + ryn1 * b2.x + rzn1 * b2.y);
          }
        }
        sacc0[mt] = a0; sacc1[mt] = a1;
      }
      sum0 += __shfl_xor(sum0, 16); sum0 += __shfl_xor(sum0, 32);
      sum1 += __shfl_xor(sum1, 16); sum1 += __shfl_xor(sum1, 32);
      fac0 = tab0[1408 + n_mine] / sum0;
      fac1 = tab1[1408 + n_mine] / sum1;
    }
    __syncthreads();   // B3: v writes + pV done; all S reads of bufB done

    if (t < 256) {
      const int tb = t >> 7, tt = t & 127;
      float* T = tb ? tab1 : tab0;
      T[384 + tt] = 1.0f / fmaxf(sqrtf(T[256 + tt]), 1e-12f);   // 1/|v|
    }
    // store normalized P -> bufB (own rows)
#pragma unroll
    for (int mt = 0; mt < 8; ++mt) {
      *(ushort4*)(bufB0 + n_mine * ROWP + 16 * mt + 4 * lg) =
          pack4(sacc0[mt][0] * fac0, sacc0[mt][1] * fac0, sacc0[mt][2] * fac0, sacc0[mt][3] * fac0);
      *(ushort4*)(bufB1 + n_mine * ROWP + 16 * mt + 4 * lg) =
          pack4(sacc1[mt][0] * fac1, sacc1[mt][1] * fac1, sacc1[mt][2] * fac1, sacc1[mt][3] * fac1);
    }
    // hoist v fragments (own rows)
    bf16x8 vf0[4], vf1[4];
#pragma unroll
    for (int kk = 0; kk < 4; ++kk) {
      vf0[kk] = *(const bf16x8*)(bufA0 + n_mine * ROWP + 8 * lg + 32 * kk);
      vf1[kk] = *(const bf16x8*)(bufA1 + n_mine * ROWP + 8 * lg + 32 * kk);
    }
    __syncthreads();   // B4: P stored, vf hoisted, sIV ready; bufA free

    // hoist P fragments (own rows)
    bf16x8 pf0[4], pf1[4];
#pragma unroll
    for (int kk = 0; kk < 4; ++kk) {
      pf0[kk] = *(const bf16x8*)(bufB0 + n_mine * ROWP + 8 * lg + 32 * kk);
      pf1[kk] = *(const bf16x8*)(bufB1 + n_mine * ROWP + 8 * lg + 32 * kk);
    }

    // ---- VW^T = (v @ W_out)^T * iv -> bufA (weights shared; prefetched) ----
    {
      const float4 iv0 = *(const float4*)&tab0[384 + 16 * w + 4 * lg];
      const float4 iv1 = *(const float4*)&tab1[384 + 16 * w + 4 * lg];
      bf16x8 bw[4], nw[4];
#pragma unroll
      for (int kk = 0; kk < 4; ++kk)
        bw[kk] = wt_frag<WS>(wtO, WoutL, lc, 8 * lg + 32 * kk, 128);
#pragma unroll 1
      for (int i = 0; i < 8; ++i) {
        if (i < 7) {
#pragma unroll
          for (int kk = 0; kk < 4; ++kk)
            nw[kk] = wt_frag<WS>(wtO, WoutL, 16 * (i + 1) + lc, 8 * lg + 32 * kk, 128);
        }
        f32x4 a0 = {0, 0, 0, 0}, a1 = {0, 0, 0, 0};
#pragma unroll
        for (int kk = 0; kk < 4; ++kk) {
          a0 = MFMA(vf0[kk], bw[kk], a0);
          a1 = MFMA(vf1[kk], bw[kk], a1);
        }
        *(ushort4*)(bufA0 + (16 * i + lc) * ROWP + 16 * w + 4 * lg) =
            pack4(a0[0] * iv0.x, a0[1] * iv0.y, a0[2] * iv0.z, a0[3] * iv0.w);
        *(ushort4*)(bufA1 + (16 * i + lc) * ROWP + 16 * w + 4 * lg) =
            pack4(a1[0] * iv1.x, a1[1] * iv1.y, a1[2] * iv1.z, a1[3] * iv1.w);
#pragma unroll
        for (int kk = 0; kk < 4; ++kk) bw[kk] = nw[kk];
      }
    }
    __syncthreads();   // B5: VW^T complete

    // ---- PV MFMAs b0/b1 INTERLEAVED; LN epilogue sequenced per b ----
    f32x4 oacc0[8], oacc1[8];
#pragma unroll 2
    for (int i = 0; i < 8; ++i) {
      bf16x8 bf0[4], bf1[4];
#pragma unroll
      for (int kk = 0; kk < 4; ++kk) {
        bf0[kk] = *(const bf16x8*)(bufA0 + (16 * i + lc) * ROWP + 8 * lg + 32 * kk);
        bf1[kk] = *(const bf16x8*)(bufA1 + (16 * i + lc) * ROWP + 8 * lg + 32 * kk);
      }
      f32x4 a0 = {0, 0, 0, 0}, a1 = {0, 0, 0, 0};
#pragma unroll
      for (int kk = 0; kk < 4; ++kk) {
        a0 = MFMA(pf0[kk], bf0[kk], a0);
        a1 = MFMA(pf1[kk], bf1[kk], a1);
      }
      oacc0[i] = a0; oacc1[i] = a1;
    }

    {
      float bo8[8], g8[8], be8[8];
#pragma unroll
      for (int ct = 0; ct < 8; ++ct) {
        const int e = 16 * ct + lc;
        bo8[ct] = boutL[e]; g8[ct] = lngL[e]; be8[ct] = lnbL[e];
      }
#pragma unroll 1
      for (int which = 0; which < 2; ++which) {
        const f32x4* oacc = which ? oacc1 : oacc0;
        const float* xsrc = which ? xsrc1 : xsrc0;
        float* xo = xout + (which ? bb1 : bb0);
#pragma unroll
        for (int r2 = 0; r2 < 4; ++r2) {
          const int n = 16 * w + 4 * lg + r2;
          const float* xr = xsrc + (size_t)n * 128;
          float vals[8];
          float s1 = 0.0f, s2 = 0.0f;
#pragma unroll
          for (int ct = 0; ct < 8; ++ct) {
            const float v = oacc[ct][r2] + bo8[ct] + xr[16 * ct + lc];
            vals[ct] = v; s1 += v; s2 += v * v;
          }
          s1 += __shfl_xor(s1, 1); s1 += __shfl_xor(s1, 2);
          s1 += __shfl_xor(s1, 4); s1 += __shfl_xor(s1, 8);
          s2 += __shfl_xor(s2, 1); s2 += __shfl_xor(s2, 2);
          s2 += __shfl_xor(s2, 4); s2 += __shfl_xor(s2, 8);
          const float mu = s1 * (1.0f / 128.0f);
          const float rs = rsqrtf(s2 * (1.0f / 128.0f) - mu * mu + F_LNEPS);
          float* orow = xo + (size_t)n * 128;
#pragma unroll
          for (int ct = 0; ct < 8; ++ct)
            orow[16 * ct + lc] = (vals[ct] - mu) * rs * g8[ct] + be8[ct];
        }
      }
    }
    __syncthreads();   // B6: layer boundary (buffers reused; xout -> next xsrc)
  }
}

extern "C" void kernel_launch(void* const* d_in, const int* in_sizes, int n_in,
                              void* d_out, int out_size, void* d_ws, size_t ws_size,
                              hipStream_t stream) {
  const float* G    = (const float*)d_in[0];
  const int*   msk  = (const int*)d_in[1];
  const float* r3   = (const float*)d_in[2];
  const float* swg  = (const float*)d_in[3];
  const float* Win  = (const float*)d_in[4];
  const float* bin  = (const float*)d_in[5];
  const float* Wout = (const float*)d_in[6];
  const float* bout = (const float*)d_in[7];
  const float* lng  = (const float*)d_in[8];
  const float* lnb  = (const float*)d_in[9];
  float* xout = (float*)d_out;

  const int B = in_sizes[0] / (128 * 128);
  const int nblk = B / 2;
  const bool ws_ok = ws_size >= (WTI_ELEMS + WTO_ELEMS) * sizeof(ushort_t);
  ushort_t* wtI = (ushort_t*)d_ws;
  ushort_t* wtO = wtI + WTI_ELEMS;

  if (ws_ok) {
    prep_weights<<<dim3(384), dim3(256), 0, stream>>>(Win, Wout, wtI, wtO);
    hipFuncSetAttribute(reinterpret_cast<const void*>(ngatt_dual<true>),
                        hipFuncAttributeMaxDynamicSharedMemorySize, LDS_BYTES);
    ngatt_dual<true><<<dim3(nblk), dim3(512), LDS_BYTES, stream>>>(
        G, msk, r3, swg, Win, bin, Wout, bout, lng, lnb, wtI, wtO, xout);
  } else {
    hipFuncSetAttribute(reinterpret_cast<const void*>(ngatt_dual<false>),
                        hipFuncAttributeMaxDynamicSharedMemorySize, LDS_BYTES);
    ngatt_dual<false><<<dim3(nblk), dim3(512), LDS_BYTES, stream>>>(
        G, msk, r3, swg, Win, bin, Wout, bout, lng, lnb, nullptr, nullptr, xout);
  }
}

// Round 11
// 2081.494 us; speedup vs baseline: 1.2449x; 1.2449x over previous
//
#include <hip/hip_runtime.h>
#include <hip/hip_bf16.h>
#include <math.h>

// NeighborGatedAttention, bf16-MFMA, DUAL-b version (R9 structure + prefetch).
// L=2, B=8192, NNEI=128, EMB=HID=128. One block (512 thr = 8 waves) handles
// TWO b's. Weight fragments shared across b0/b1 (2x MFMA per weight load).
// vs R9: explicit next-tile weight prefetch in q/k/v and VW loops (+16 regs
// transient, loops' live sets ~80 so it fits); pf hoist delayed to after B5
// (frees 32 regs during VW). S and PV remain SEQUENCED per b -- R10 proved
// the interleaved form exceeds the ~128-arch allocator ceiling and spills.
// LDS 154.6KB. 1 block/CU, 2 waves/SIMD (256-reg budget).
// All GEMMs v_mfma_f32_16x16x32_bf16; l2-norms from fp32 accs; softmax/LN fp32.

typedef __attribute__((ext_vector_type(8))) short bf16x8; // 8 bf16 = 4 VGPR
typedef __attribute__((ext_vector_type(4))) float f32x4;
typedef unsigned short ushort_t;

constexpr float F_SHIFT   = 20.0f;
constexpr float F_SCALING = 0.08838834764831845f; // 128^-0.5
constexpr float F_LNEPS   = 1e-5f;

constexpr int ROWP = 136;                 // ushort row pitch (272B)
constexpr int BUF_US = 128 * ROWP;        // 17408 ushorts per buffer
constexpr size_t WTI_ELEMS = 2 * 384 * 128;
constexpr size_t WTO_ELEMS = 2 * 128 * 128;
constexpr int TAB_F = 1920;               // per-b table floats
constexpr int LDS_BYTES = 4 * BUF_US * 2 + 2 * TAB_F * 4; // 154624

#define MFMA(a, b, c) __builtin_amdgcn_mfma_f32_16x16x32_bf16(a, b, c, 0, 0, 0)

__device__ __forceinline__ ushort_t f2bf(float f) {
  __hip_bfloat16 h = __float2bfloat16(f);
  return *reinterpret_cast<ushort_t*>(&h);
}
__device__ __forceinline__ ushort4 pack4(float a, float b, float c, float d) {
  return make_ushort4(f2bf(a), f2bf(b), f2bf(c), f2bf(d));
}

// A/B fragment from pre-transposed bf16 weights (WS) or fp32 gather fallback.
template <bool WS>
__device__ __forceinline__ bf16x8 wt_frag(const ushort_t* __restrict__ wt,
                                          const float* __restrict__ W,
                                          int r, int c, int ldW) {
  if constexpr (WS) {
    return *(const bf16x8*)(wt + r * 128 + c);
  } else {
    bf16x8 f;
#pragma unroll
    for (int j = 0; j < 8; ++j) f[j] = (short)f2bf(W[(size_t)(c + j) * ldW + r]);
    return f;
  }
}

__global__ void prep_weights(const float* __restrict__ Win, const float* __restrict__ Wout,
                             ushort_t* __restrict__ wtI, ushort_t* __restrict__ wtO) {
  const int i = blockIdx.x * 256 + threadIdx.x;
  if (i < (int)WTI_ELEMS) {   // wtI[l][h][e] = bf16(Win[l][e][h])
    const int l = i / (384 * 128), r = i % (384 * 128), h = r >> 7, e = r & 127;
    wtI[i] = f2bf(Win[l * (128 * 384) + e * 384 + h]);
  }
  if (i < (int)WTO_ELEMS) {   // wtO[l][e][h] = bf16(Wout[l][h][e])
    const int l = i >> 14, r = i & 16383, e = r >> 7, h = r & 127;
    wtO[i] = f2bf(Wout[(l << 14) + h * 128 + e]);
  }
}

__device__ __forceinline__ bf16x8 load_xf(const float* xr) {
  const float4 a = *(const float4*)xr;
  const float4 c = *(const float4*)(xr + 4);
  bf16x8 f;
  f[0] = (short)f2bf(a.x); f[1] = (short)f2bf(a.y);
  f[2] = (short)f2bf(a.z); f[3] = (short)f2bf(a.w);
  f[4] = (short)f2bf(c.x); f[5] = (short)f2bf(c.y);
  f[6] = (short)f2bf(c.z); f[7] = (short)f2bf(c.w);
  return f;
}

template <bool WS>
__global__ __launch_bounds__(512, 2)
void ngatt_dual(const float* __restrict__ G, const int* __restrict__ nmask,
                const float* __restrict__ r3, const float* __restrict__ swg,
                const float* __restrict__ Win, const float* __restrict__ bin,
                const float* __restrict__ Wout, const float* __restrict__ bout,
                const float* __restrict__ lng, const float* __restrict__ lnb,
                const ushort_t* __restrict__ wtin, const ushort_t* __restrict__ wtout,
                float* __restrict__ xout) {
  extern __shared__ char smem[];
  ushort_t* bufA0 = (ushort_t*)smem;           // b0: q -> v -> VW^T
  ushort_t* bufB0 = bufA0 + BUF_US;            // b0: k -> P
  ushort_t* bufA1 = bufB0 + BUF_US;            // b1: q -> v -> VW^T
  ushort_t* bufB1 = bufA1 + BUF_US;            // b1: k -> P
  float* tab0 = (float*)(bufB1 + BUF_US);
  float* tab1 = tab0 + TAB_F;
  // per-b table layout (float offsets):
  //   pQ 0, pK 128, pV 256, sIV 384, fA 512..1023, fB 1024..1279,
  //   sSW 1280, sMK 1408, sRX 1536, sRY 1664, sRZ 1792

  const int bid = blockIdx.x, t = threadIdx.x;
  const int w = t >> 6, l = t & 63, lc = l & 15, lg = l >> 4;
  const int b0 = 2 * bid, b1 = b0 + 1;
  const size_t bb0 = (size_t)b0 * (128 * 128);
  const size_t bb1 = (size_t)b1 * (128 * 128);
  const int n_mine = 16 * w + lc;

  if (t < 256) {
    const int tb = t >> 7, tt = t & 127;
    float* T = tb ? tab1 : tab0;
    const size_t gi = (size_t)(b0 + tb) * 128 + tt;
    T[1280 + tt] = swg[gi];
    T[1408 + tt] = nmask[gi] ? 1.0f : 0.0f;
    T[1536 + tt] = r3[gi * 3 + 0];
    T[1664 + tt] = r3[gi * 3 + 1];
    T[1792 + tt] = r3[gi * 3 + 2];
  }
  __syncthreads();

  for (int layer = 0; layer < 2; ++layer) {
    const float* xsrc0 = layer ? (xout + bb0) : (G + bb0);
    const float* xsrc1 = layer ? (xout + bb1) : (G + bb1);
    const ushort_t* wtI = wtin + (size_t)layer * 384 * 128;
    const ushort_t* wtO = wtout + (size_t)layer * 128 * 128;
    const float* WinL  = Win  + (size_t)layer * 128 * 384;
    const float* WoutL = Wout + (size_t)layer * 128 * 128;
    const float* binL  = bin  + layer * 384;
    const float* boutL = bout + layer * 128;
    const float* lngL  = lng  + layer * 128;
    const float* lnbL  = lnb  + layer * 128;

    // ---- hoist x B-fragments for both b's (col n_mine) ----
    bf16x8 xf0[4], xf1[4];
#pragma unroll
    for (int kk = 0; kk < 4; ++kk) {
      xf0[kk] = load_xf(xsrc0 + (size_t)n_mine * 128 + 8 * lg + 32 * kk);
      xf1[kk] = load_xf(xsrc1 + (size_t)n_mine * 128 + 8 * lg + 32 * kk);
    }

    // ---- q: tiles 0..7 -> bufA0/bufA1 (weights shared; prefetched) ----
    float ssq0 = 0.f, ssq1 = 0.f, ssk0 = 0.f, ssk1 = 0.f;
    {
      bf16x8 aw[4], nw[4];
#pragma unroll
      for (int kk = 0; kk < 4; ++kk)
        aw[kk] = wt_frag<WS>(wtI, WinL, lc, 8 * lg + 32 * kk, 384);
#pragma unroll 1
      for (int i = 0; i < 8; ++i) {
        if (i < 7) {
#pragma unroll
          for (int kk = 0; kk < 4; ++kk)
            nw[kk] = wt_frag<WS>(wtI, WinL, 16 * (i + 1) + lc, 8 * lg + 32 * kk, 384);
        }
        f32x4 a0 = {0, 0, 0, 0}, a1 = {0, 0, 0, 0};
#pragma unroll
        for (int kk = 0; kk < 4; ++kk) {
          a0 = MFMA(aw[kk], xf0[kk], a0);
          a1 = MFMA(aw[kk], xf1[kk], a1);
        }
        const float4 bi = *(const float4*)&binL[16 * i + 4 * lg];
        {
          const float v0 = a0[0] + bi.x, v1 = a0[1] + bi.y, v2 = a0[2] + bi.z, v3 = a0[3] + bi.w;
          ssq0 += v0 * v0 + v1 * v1 + v2 * v2 + v3 * v3;
          *(ushort4*)(bufA0 + n_mine * ROWP + 16 * i + 4 * lg) = pack4(v0, v1, v2, v3);
        }
        {
          const float v0 = a1[0] + bi.x, v1 = a1[1] + bi.y, v2 = a1[2] + bi.z, v3 = a1[3] + bi.w;
          ssq1 += v0 * v0 + v1 * v1 + v2 * v2 + v3 * v3;
          *(ushort4*)(bufA1 + n_mine * ROWP + 16 * i + 4 * lg) = pack4(v0, v1, v2, v3);
        }
#pragma unroll
        for (int kk = 0; kk < 4; ++kk) aw[kk] = nw[kk];
      }
    }
    // ---- k: tiles 8..15 -> bufB0/bufB1 (prefetched) ----
    {
      bf16x8 aw[4], nw[4];
#pragma unroll
      for (int kk = 0; kk < 4; ++kk)
        aw[kk] = wt_frag<WS>(wtI, WinL, 128 + lc, 8 * lg + 32 * kk, 384);
#pragma unroll 1
      for (int i = 0; i < 8; ++i) {
        if (i < 7) {
#pragma unroll
          for (int kk = 0; kk < 4; ++kk)
            nw[kk] = wt_frag<WS>(wtI, WinL, 128 + 16 * (i + 1) + lc, 8 * lg + 32 * kk, 384);
        }
        f32x4 a0 = {0, 0, 0, 0}, a1 = {0, 0, 0, 0};
#pragma unroll
        for (int kk = 0; kk < 4; ++kk) {
          a0 = MFMA(aw[kk], xf0[kk], a0);
          a1 = MFMA(aw[kk], xf1[kk], a1);
        }
        const float4 bi = *(const float4*)&binL[128 + 16 * i + 4 * lg];
        {
          const float v0 = a0[0] + bi.x, v1 = a0[1] + bi.y, v2 = a0[2] + bi.z, v3 = a0[3] + bi.w;
          ssk0 += v0 * v0 + v1 * v1 + v2 * v2 + v3 * v3;
          *(ushort4*)(bufB0 + n_mine * ROWP + 16 * i + 4 * lg) = pack4(v0, v1, v2, v3);
        }
        {
          const float v0 = a1[0] + bi.x, v1 = a1[1] + bi.y, v2 = a1[2] + bi.z, v3 = a1[3] + bi.w;
          ssk1 += v0 * v0 + v1 * v1 + v2 * v2 + v3 * v3;
          *(ushort4*)(bufB1 + n_mine * ROWP + 16 * i + 4 * lg) = pack4(v0, v1, v2, v3);
        }
#pragma unroll
        for (int kk = 0; kk < 4; ++kk) aw[kk] = nw[kk];
      }
    }
    ssq0 += __shfl_xor(ssq0, 16); ssq0 += __shfl_xor(ssq0, 32);
    ssq1 += __shfl_xor(ssq1, 16); ssq1 += __shfl_xor(ssq1, 32);
    ssk0 += __shfl_xor(ssk0, 16); ssk0 += __shfl_xor(ssk0, 32);
    ssk1 += __shfl_xor(ssk1, 16); ssk1 += __shfl_xor(ssk1, 32);
    if (l < 16) {
      tab0[0 + n_mine] = ssq0; tab0[128 + n_mine] = ssk0;
      tab1[0 + n_mine] = ssq1; tab1[128 + n_mine] = ssk1;
    }
    __syncthreads();   // B1: q,k complete + norm partials

    if (t < 256) {
      const int tb = t >> 7, tt = t & 127;
      float* T = tb ? tab1 : tab0;
      T[0 + tt] = 1.0f / fmaxf(sqrtf(T[0 + tt]), 1e-12f);                 // 1/|q|
      T[512 + 4 * tt + 0] = (1.0f / fmaxf(sqrtf(T[128 + tt]), 1e-12f)) * F_SCALING;
      T[512 + 4 * tt + 1] = T[1280 + tt];   // sw
      T[512 + 4 * tt + 2] = 0.0f;
      T[512 + 4 * tt + 3] = T[1536 + tt];   // rx
      T[1024 + 2 * tt + 0] = T[1664 + tt];  // ry
      T[1024 + 2 * tt + 1] = T[1792 + tt];  // rz
    }
    // hoist q fragments for both b's (own rows)
    bf16x8 qf0[4], qf1[4];
#pragma unroll
    for (int kk = 0; kk < 4; ++kk) {
      qf0[kk] = *(const bf16x8*)(bufA0 + n_mine * ROWP + 8 * lg + 32 * kk);
      qf1[kk] = *(const bf16x8*)(bufA1 + n_mine * ROWP + 8 * lg + 32 * kk);
    }
    __syncthreads();   // B2: qf hoisted; factor tables ready; bufA free

    // ---- v: tiles 16..23 -> bufA0/bufA1 (weights shared; prefetched) ----
    float ssv0 = 0.f, ssv1 = 0.f;
    {
      bf16x8 aw[4], nw[4];
#pragma unroll
      for (int kk = 0; kk < 4; ++kk)
        aw[kk] = wt_frag<WS>(wtI, WinL, 256 + lc, 8 * lg + 32 * kk, 384);
#pragma unroll 1
      for (int i = 0; i < 8; ++i) {
        if (i < 7) {
#pragma unroll
          for (int kk = 0; kk < 4; ++kk)
            nw[kk] = wt_frag<WS>(wtI, WinL, 256 + 16 * (i + 1) + lc, 8 * lg + 32 * kk, 384);
        }
        f32x4 a0 = {0, 0, 0, 0}, a1 = {0, 0, 0, 0};
#pragma unroll
        for (int kk = 0; kk < 4; ++kk) {
          a0 = MFMA(aw[kk], xf0[kk], a0);
          a1 = MFMA(aw[kk], xf1[kk], a1);
        }
        const float4 bi = *(const float4*)&binL[256 + 16 * i + 4 * lg];
        {
          const float v0 = a0[0] + bi.x, v1 = a0[1] + bi.y, v2 = a0[2] + bi.z, v3 = a0[3] + bi.w;
          ssv0 += v0 * v0 + v1 * v1 + v2 * v2 + v3 * v3;
          *(ushort4*)(bufA0 + n_mine * ROWP + 16 * i + 4 * lg) = pack4(v0, v1, v2, v3);
        }
        {
          const float v0 = a1[0] + bi.x, v1 = a1[1] + bi.y, v2 = a1[2] + bi.z, v3 = a1[3] + bi.w;
          ssv1 += v0 * v0 + v1 * v1 + v2 * v2 + v3 * v3;
          *(ushort4*)(bufA1 + n_mine * ROWP + 16 * i + 4 * lg) = pack4(v0, v1, v2, v3);
        }
#pragma unroll
        for (int kk = 0; kk < 4; ++kk) aw[kk] = nw[kk];
      }
    }
    ssv0 += __shfl_xor(ssv0, 16); ssv0 += __shfl_xor(ssv0, 32);
    ssv1 += __shfl_xor(ssv1, 16); ssv1 += __shfl_xor(ssv1, 32);
    if (l < 16) { tab0[256 + n_mine] = ssv0; tab1[256 + n_mine] = ssv1; }

    // ---- S + softmax, b0 then b1 (SEQUENCED to cap registers) ----
    f32x4 sacc0[8], sacc1[8];
    float fac0, fac1;
    {
      const float iqn = tab0[0 + n_mine];
      const float swn = tab0[1280 + n_mine];
      const float rxn = tab0[1536 + n_mine], ryn = tab0[1664 + n_mine], rzn = tab0[1792 + n_mine];
      float sum = 0.0f;
#pragma unroll 2
      for (int mt = 0; mt < 8; ++mt) {
        bf16x8 kf[4];
#pragma unroll
        for (int kk = 0; kk < 4; ++kk)
          kf[kk] = *(const bf16x8*)(bufB0 + (16 * mt + lc) * ROWP + 8 * lg + 32 * kk);
        f32x4 a = {0, 0, 0, 0};
#pragma unroll
        for (int kk = 0; kk < 4; ++kk) a = MFMA(kf[kk], qf0[kk], a);
#pragma unroll
        for (int r2 = 0; r2 < 4; ++r2) {
          const int m = 16 * mt + 4 * lg + r2;
          const float4 a4 = *(const float4*)&tab0[512 + 4 * m];
          const float2 b2 = *(const float2*)&tab0[1024 + 2 * m];
          const float sws = swn * a4.y;
          const float e = __expf((a[r2] * iqn * a4.x + F_SHIFT) * sws - F_SHIFT);
          sum += e;
          a[r2] = e * sws * (rxn * a4.w + ryn * b2.x + rzn * b2.y);
        }
        sacc0[mt] = a;
      }
      sum += __shfl_xor(sum, 16); sum += __shfl_xor(sum, 32);
      fac0 = tab0[1408 + n_mine] / sum;
    }
    {
      const float iqn = tab1[0 + n_mine];
      const float swn = tab1[1280 + n_mine];
      const float rxn = tab1[1536 + n_mine], ryn = tab1[1664 + n_mine], rzn = tab1[1792 + n_mine];
      float sum = 0.0f;
#pragma unroll 2
      for (int mt = 0; mt < 8; ++mt) {
        bf16x8 kf[4];
#pragma unroll
        for (int kk = 0; kk < 4; ++kk)
          kf[kk] = *(const bf16x8*)(bufB1 + (16 * mt + lc) * ROWP + 8 * lg + 32 * kk);
        f32x4 a = {0, 0, 0, 0};
#pragma unroll
        for (int kk = 0; kk < 4; ++kk) a = MFMA(kf[kk], qf1[kk], a);
#pragma unroll
        for (int r2 = 0; r2 < 4; ++r2) {
          const int m = 16 * mt + 4 * lg + r2;
          const float4 a4 = *(const float4*)&tab1[512 + 4 * m];
          const float2 b2 = *(const float2*)&tab1[1024 + 2 * m];
          const float sws = swn * a4.y;
          const float e = __expf((a[r2] * iqn * a4.x + F_SHIFT) * sws - F_SHIFT);
          sum += e;
          a[r2] = e * sws * (rxn * a4.w + ryn * b2.x + rzn * b2.y);
        }
        sacc1[mt] = a;
      }
      sum += __shfl_xor(sum, 16); sum += __shfl_xor(sum, 32);
      fac1 = tab1[1408 + n_mine] / sum;
    }
    __syncthreads();   // B3: v writes + pV done; all S reads of bufB done

    if (t < 256) {
      const int tb = t >> 7, tt = t & 127;
      float* T = tb ? tab1 : tab0;
      T[384 + tt] = 1.0f / fmaxf(sqrtf(T[256 + tt]), 1e-12f);   // 1/|v|
    }
    // store normalized P -> bufB (own rows)
#pragma unroll
    for (int mt = 0; mt < 8; ++mt) {
      *(ushort4*)(bufB0 + n_mine * ROWP + 16 * mt + 4 * lg) =
          pack4(sacc0[mt][0] * fac0, sacc0[mt][1] * fac0, sacc0[mt][2] * fac0, sacc0[mt][3] * fac0);
      *(ushort4*)(bufB1 + n_mine * ROWP + 16 * mt + 4 * lg) =
          pack4(sacc1[mt][0] * fac1, sacc1[mt][1] * fac1, sacc1[mt][2] * fac1, sacc1[mt][3] * fac1);
    }
    // hoist v fragments (own rows)
    bf16x8 vf0[4], vf1[4];
#pragma unroll
    for (int kk = 0; kk < 4; ++kk) {
      vf0[kk] = *(const bf16x8*)(bufA0 + n_mine * ROWP + 8 * lg + 32 * kk);
      vf1[kk] = *(const bf16x8*)(bufA1 + n_mine * ROWP + 8 * lg + 32 * kk);
    }
    __syncthreads();   // B4: P stored, vf hoisted, sIV ready; bufA free

    // ---- VW^T = (v @ W_out)^T * iv -> bufA (weights shared; prefetched) ----
    {
      const float4 iv0 = *(const float4*)&tab0[384 + 16 * w + 4 * lg];
      const float4 iv1 = *(const float4*)&tab1[384 + 16 * w + 4 * lg];
      bf16x8 bw[4], nw[4];
#pragma unroll
      for (int kk = 0; kk < 4; ++kk)
        bw[kk] = wt_frag<WS>(wtO, WoutL, lc, 8 * lg + 32 * kk, 128);
#pragma unroll 1
      for (int i = 0; i < 8; ++i) {
        if (i < 7) {
#pragma unroll
          for (int kk = 0; kk < 4; ++kk)
            nw[kk] = wt_frag<WS>(wtO, WoutL, 16 * (i + 1) + lc, 8 * lg + 32 * kk, 128);
        }
        f32x4 a0 = {0, 0, 0, 0}, a1 = {0, 0, 0, 0};
#pragma unroll
        for (int kk = 0; kk < 4; ++kk) {
          a0 = MFMA(vf0[kk], bw[kk], a0);
          a1 = MFMA(vf1[kk], bw[kk], a1);
        }
        *(ushort4*)(bufA0 + (16 * i + lc) * ROWP + 16 * w + 4 * lg) =
            pack4(a0[0] * iv0.x, a0[1] * iv0.y, a0[2] * iv0.z, a0[3] * iv0.w);
        *(ushort4*)(bufA1 + (16 * i + lc) * ROWP + 16 * w + 4 * lg) =
            pack4(a1[0] * iv1.x, a1[1] * iv1.y, a1[2] * iv1.z, a1[3] * iv1.w);
#pragma unroll
        for (int kk = 0; kk < 4; ++kk) bw[kk] = nw[kk];
      }
    }
    __syncthreads();   // B5: VW^T complete

    // hoist P fragments (own rows; bufB untouched since P store)
    bf16x8 pf0[4], pf1[4];
#pragma unroll
    for (int kk = 0; kk < 4; ++kk) {
      pf0[kk] = *(const bf16x8*)(bufB0 + n_mine * ROWP + 8 * lg + 32 * kk);
      pf1[kk] = *(const bf16x8*)(bufB1 + n_mine * ROWP + 8 * lg + 32 * kk);
    }

    // ---- PV + LN epilogue, b0 then b1 (SEQUENCED) ----
    float bo8[8], g8[8], be8[8];
#pragma unroll
    for (int ct = 0; ct < 8; ++ct) {
      const int e = 16 * ct + lc;
      bo8[ct] = boutL[e]; g8[ct] = lngL[e]; be8[ct] = lnbL[e];
    }
#pragma unroll 1
    for (int which = 0; which < 2; ++which) {
      const ushort_t* bufA = which ? bufA1 : bufA0;
      const float* xsrc = which ? xsrc1 : xsrc0;
      float* xo = xout + (which ? bb1 : bb0);
      f32x4 oacc[8];
#pragma unroll 2
      for (int i = 0; i < 8; ++i) {
        bf16x8 bf[4];
#pragma unroll
        for (int kk = 0; kk < 4; ++kk)
          bf[kk] = *(const bf16x8*)(bufA + (16 * i + lc) * ROWP + 8 * lg + 32 * kk);
        f32x4 a = {0, 0, 0, 0};
        if (which == 0) {
#pragma unroll
          for (int kk = 0; kk < 4; ++kk) a = MFMA(pf0[kk], bf[kk], a);
        } else {
#pragma unroll
          for (int kk = 0; kk < 4; ++kk) a = MFMA(pf1[kk], bf[kk], a);
        }
        oacc[i] = a;
      }
#pragma unroll
      for (int r2 = 0; r2 < 4; ++r2) {
        const int n = 16 * w + 4 * lg + r2;
        const float* xr = xsrc + (size_t)n * 128;
        float vals[8];
        float s1 = 0.0f, s2 = 0.0f;
#pragma unroll
        for (int ct = 0; ct < 8; ++ct) {
          const float v = oacc[ct][r2] + bo8[ct] + xr[16 * ct + lc];
          vals[ct] = v; s1 += v; s2 += v * v;
        }
        s1 += __shfl_xor(s1, 1); s1 += __shfl_xor(s1, 2);
        s1 += __shfl_xor(s1, 4); s1 += __shfl_xor(s1, 8);
        s2 += __shfl_xor(s2, 1); s2 += __shfl_xor(s2, 2);
        s2 += __shfl_xor(s2, 4); s2 += __shfl_xor(s2, 8);
        const float mu = s1 * (1.0f / 128.0f);
        const float rs = rsqrtf(s2 * (1.0f / 128.0f) - mu * mu + F_LNEPS);
        float* orow = xo + (size_t)n * 128;
#pragma unroll
        for (int ct = 0; ct < 8; ++ct)
          orow[16 * ct + lc] = (vals[ct] - mu) * rs * g8[ct] + be8[ct];
      }
    }
    __syncthreads();   // B6: layer boundary (buffers reused; xout -> next xsrc)
  }
}

extern "C" void kernel_launch(void* const* d_in, const int* in_sizes, int n_in,
                              void* d_out, int out_size, void* d_ws, size_t ws_size,
                              hipStream_t stream) {
  const float* G    = (const float*)d_in[0];
  const int*   msk  = (const int*)d_in[1];
  const float* r3   = (const float*)d_in[2];
  const float* swg  = (const float*)d_in[3];
  const float* Win  = (const float*)d_in[4];
  const float* bin  = (const float*)d_in[5];
  const float* Wout = (const float*)d_in[6];
  const float* bout = (const float*)d_in[7];
  const float* lng  = (const float*)d_in[8];
  const float* lnb  = (const float*)d_in[9];
  float* xout = (float*)d_out;

  const int B = in_sizes[0] / (128 * 128);
  const int nblk = B / 2;
  const bool ws_ok = ws_size >= (WTI_ELEMS + WTO_ELEMS) * sizeof(ushort_t);
  ushort_t* wtI = (ushort_t*)d_ws;
  ushort_t* wtO = wtI + WTI_ELEMS;

  if (ws_ok) {
    prep_weights<<<dim3(384), dim3(256), 0, stream>>>(Win, Wout, wtI, wtO);
    hipFuncSetAttribute(reinterpret_cast<const void*>(ngatt_dual<true>),
                        hipFuncAttributeMaxDynamicSharedMemorySize, LDS_BYTES);
    ngatt_dual<true><<<dim3(nblk), dim3(512), LDS_BYTES, stream>>>(
        G, msk, r3, swg, Win, bin, Wout, bout, lng, lnb, wtI, wtO, xout);
  } else {
    hipFuncSetAttribute(reinterpret_cast<const void*>(ngatt_dual<false>),
                        hipFuncAttributeMaxDynamicSharedMemorySize, LDS_BYTES);
    ngatt_dual<false><<<dim3(nblk), dim3(512), LDS_BYTES, stream>>>(
        G, msk, r3, swg, Win, bin, Wout, bout, lng, lnb, nullptr, nullptr, xout);
  }
}

// Round 12
// 2007.273 us; speedup vs baseline: 1.2910x; 1.0370x over previous
//
#include <hip/hip_runtime.h>
#include <hip/hip_bf16.h>
#include <math.h>

// NeighborGatedAttention, bf16-MFMA, DUAL-b (R9 structure, surgical edits).
// L=2, B=8192, NNEI=128, EMB=HID=128. One block (512 thr = 8 waves), TWO b's.
// vs R9: (1) next-tile weight prefetch in q/k and VW loops ONLY (their live
// sets ~115/~90 afford +16; R11 proved prefetch in the v loop spills --
// xf+qf+aw/nw ~130 > ~128 ceiling); (2) early P packing: after each S_b row
// sum, pack4(...*fac) into ushort4 p[8] (16 regs) immediately -- sacc fp32
// (32 regs) dies before the next sub-phase; (3) pf hoist after B5.
// S and PV remain SEQUENCED per b. LDS 154.6KB, 1 block/CU, 2 waves/SIMD.
// All GEMMs v_mfma_f32_16x16x32_bf16; l2-norms from fp32 accs; softmax/LN fp32.

typedef __attribute__((ext_vector_type(8))) short bf16x8; // 8 bf16 = 4 VGPR
typedef __attribute__((ext_vector_type(4))) float f32x4;
typedef unsigned short ushort_t;

constexpr float F_SHIFT   = 20.0f;
constexpr float F_SCALING = 0.08838834764831845f; // 128^-0.5
constexpr float F_LNEPS   = 1e-5f;

constexpr int ROWP = 136;                 // ushort row pitch (272B)
constexpr int BUF_US = 128 * ROWP;        // 17408 ushorts per buffer
constexpr size_t WTI_ELEMS = 2 * 384 * 128;
constexpr size_t WTO_ELEMS = 2 * 128 * 128;
constexpr int TAB_F = 1920;               // per-b table floats
constexpr int LDS_BYTES = 4 * BUF_US * 2 + 2 * TAB_F * 4; // 154624

#define MFMA(a, b, c) __builtin_amdgcn_mfma_f32_16x16x32_bf16(a, b, c, 0, 0, 0)

__device__ __forceinline__ ushort_t f2bf(float f) {
  __hip_bfloat16 h = __float2bfloat16(f);
  return *reinterpret_cast<ushort_t*>(&h);
}
__device__ __forceinline__ ushort4 pack4(float a, float b, float c, float d) {
  return make_ushort4(f2bf(a), f2bf(b), f2bf(c), f2bf(d));
}

// A/B fragment from pre-transposed bf16 weights (WS) or fp32 gather fallback.
template <bool WS>
__device__ __forceinline__ bf16x8 wt_frag(const ushort_t* __restrict__ wt,
                                          const float* __restrict__ W,
                                          int r, int c, int ldW) {
  if constexpr (WS) {
    return *(const bf16x8*)(wt + r * 128 + c);
  } else {
    bf16x8 f;
#pragma unroll
    for (int j = 0; j < 8; ++j) f[j] = (short)f2bf(W[(size_t)(c + j) * ldW + r]);
    return f;
  }
}

__global__ void prep_weights(const float* __restrict__ Win, const float* __restrict__ Wout,
                             ushort_t* __restrict__ wtI, ushort_t* __restrict__ wtO) {
  const int i = blockIdx.x * 256 + threadIdx.x;
  if (i < (int)WTI_ELEMS) {   // wtI[l][h][e] = bf16(Win[l][e][h])
    const int l = i / (384 * 128), r = i % (384 * 128), h = r >> 7, e = r & 127;
    wtI[i] = f2bf(Win[l * (128 * 384) + e * 384 + h]);
  }
  if (i < (int)WTO_ELEMS) {   // wtO[l][e][h] = bf16(Wout[l][h][e])
    const int l = i >> 14, r = i & 16383, e = r >> 7, h = r & 127;
    wtO[i] = f2bf(Wout[(l << 14) + h * 128 + e]);
  }
}

__device__ __forceinline__ bf16x8 load_xf(const float* xr) {
  const float4 a = *(const float4*)xr;
  const float4 c = *(const float4*)(xr + 4);
  bf16x8 f;
  f[0] = (short)f2bf(a.x); f[1] = (short)f2bf(a.y);
  f[2] = (short)f2bf(a.z); f[3] = (short)f2bf(a.w);
  f[4] = (short)f2bf(c.x); f[5] = (short)f2bf(c.y);
  f[6] = (short)f2bf(c.z); f[7] = (short)f2bf(c.w);
  return f;
}

template <bool WS>
__global__ __launch_bounds__(512, 2)
void ngatt_dual(const float* __restrict__ G, const int* __restrict__ nmask,
                const float* __restrict__ r3, const float* __restrict__ swg,
                const float* __restrict__ Win, const float* __restrict__ bin,
                const float* __restrict__ Wout, const float* __restrict__ bout,
                const float* __restrict__ lng, const float* __restrict__ lnb,
                const ushort_t* __restrict__ wtin, const ushort_t* __restrict__ wtout,
                float* __restrict__ xout) {
  extern __shared__ char smem[];
  ushort_t* bufA0 = (ushort_t*)smem;           // b0: q -> v -> VW^T
  ushort_t* bufB0 = bufA0 + BUF_US;            // b0: k -> P
  ushort_t* bufA1 = bufB0 + BUF_US;            // b1: q -> v -> VW^T
  ushort_t* bufB1 = bufA1 + BUF_US;            // b1: k -> P
  float* tab0 = (float*)(bufB1 + BUF_US);
  float* tab1 = tab0 + TAB_F;
  // per-b table layout (float offsets):
  //   pQ 0, pK 128, pV 256, sIV 384, fA 512..1023, fB 1024..1279,
  //   sSW 1280, sMK 1408, sRX 1536, sRY 1664, sRZ 1792

  const int bid = blockIdx.x, t = threadIdx.x;
  const int w = t >> 6, l = t & 63, lc = l & 15, lg = l >> 4;
  const int b0 = 2 * bid, b1 = b0 + 1;
  const size_t bb0 = (size_t)b0 * (128 * 128);
  const size_t bb1 = (size_t)b1 * (128 * 128);
  const int n_mine = 16 * w + lc;

  if (t < 256) {
    const int tb = t >> 7, tt = t & 127;
    float* T = tb ? tab1 : tab0;
    const size_t gi = (size_t)(b0 + tb) * 128 + tt;
    T[1280 + tt] = swg[gi];
    T[1408 + tt] = nmask[gi] ? 1.0f : 0.0f;
    T[1536 + tt] = r3[gi * 3 + 0];
    T[1664 + tt] = r3[gi * 3 + 1];
    T[1792 + tt] = r3[gi * 3 + 2];
  }
  __syncthreads();

  for (int layer = 0; layer < 2; ++layer) {
    const float* xsrc0 = layer ? (xout + bb0) : (G + bb0);
    const float* xsrc1 = layer ? (xout + bb1) : (G + bb1);
    const ushort_t* wtI = wtin + (size_t)layer * 384 * 128;
    const ushort_t* wtO = wtout + (size_t)layer * 128 * 128;
    const float* WinL  = Win  + (size_t)layer * 128 * 384;
    const float* WoutL = Wout + (size_t)layer * 128 * 128;
    const float* binL  = bin  + layer * 384;
    const float* boutL = bout + layer * 128;
    const float* lngL  = lng  + layer * 128;
    const float* lnbL  = lnb  + layer * 128;

    // ---- hoist x B-fragments for both b's (col n_mine) ----
    bf16x8 xf0[4], xf1[4];
#pragma unroll
    for (int kk = 0; kk < 4; ++kk) {
      xf0[kk] = load_xf(xsrc0 + (size_t)n_mine * 128 + 8 * lg + 32 * kk);
      xf1[kk] = load_xf(xsrc1 + (size_t)n_mine * 128 + 8 * lg + 32 * kk);
    }

    // ---- q: tiles 0..7 -> bufA0/bufA1 (weights shared; PREFETCHED) ----
    float ssq0 = 0.f, ssq1 = 0.f, ssk0 = 0.f, ssk1 = 0.f;
    {
      bf16x8 aw[4], nw[4];
#pragma unroll
      for (int kk = 0; kk < 4; ++kk)
        aw[kk] = wt_frag<WS>(wtI, WinL, lc, 8 * lg + 32 * kk, 384);
#pragma unroll 1
      for (int i = 0; i < 8; ++i) {
        if (i < 7) {
#pragma unroll
          for (int kk = 0; kk < 4; ++kk)
            nw[kk] = wt_frag<WS>(wtI, WinL, 16 * (i + 1) + lc, 8 * lg + 32 * kk, 384);
        }
        f32x4 a0 = {0, 0, 0, 0}, a1 = {0, 0, 0, 0};
#pragma unroll
        for (int kk = 0; kk < 4; ++kk) {
          a0 = MFMA(aw[kk], xf0[kk], a0);
          a1 = MFMA(aw[kk], xf1[kk], a1);
        }
        const float4 bi = *(const float4*)&binL[16 * i + 4 * lg];
        {
          const float v0 = a0[0] + bi.x, v1 = a0[1] + bi.y, v2 = a0[2] + bi.z, v3 = a0[3] + bi.w;
          ssq0 += v0 * v0 + v1 * v1 + v2 * v2 + v3 * v3;
          *(ushort4*)(bufA0 + n_mine * ROWP + 16 * i + 4 * lg) = pack4(v0, v1, v2, v3);
        }
        {
          const float v0 = a1[0] + bi.x, v1 = a1[1] + bi.y, v2 = a1[2] + bi.z, v3 = a1[3] + bi.w;
          ssq1 += v0 * v0 + v1 * v1 + v2 * v2 + v3 * v3;
          *(ushort4*)(bufA1 + n_mine * ROWP + 16 * i + 4 * lg) = pack4(v0, v1, v2, v3);
        }
#pragma unroll
        for (int kk = 0; kk < 4; ++kk) aw[kk] = nw[kk];
      }
    }
    // ---- k: tiles 8..15 -> bufB0/bufB1 (PREFETCHED) ----
    {
      bf16x8 aw[4], nw[4];
#pragma unroll
      for (int kk = 0; kk < 4; ++kk)
        aw[kk] = wt_frag<WS>(wtI, WinL, 128 + lc, 8 * lg + 32 * kk, 384);
#pragma unroll 1
      for (int i = 0; i < 8; ++i) {
        if (i < 7) {
#pragma unroll
          for (int kk = 0; kk < 4; ++kk)
            nw[kk] = wt_frag<WS>(wtI, WinL, 128 + 16 * (i + 1) + lc, 8 * lg + 32 * kk, 384);
        }
        f32x4 a0 = {0, 0, 0, 0}, a1 = {0, 0, 0, 0};
#pragma unroll
        for (int kk = 0; kk < 4; ++kk) {
          a0 = MFMA(aw[kk], xf0[kk], a0);
          a1 = MFMA(aw[kk], xf1[kk], a1);
        }
        const float4 bi = *(const float4*)&binL[128 + 16 * i + 4 * lg];
        {
          const float v0 = a0[0] + bi.x, v1 = a0[1] + bi.y, v2 = a0[2] + bi.z, v3 = a0[3] + bi.w;
          ssk0 += v0 * v0 + v1 * v1 + v2 * v2 + v3 * v3;
          *(ushort4*)(bufB0 + n_mine * ROWP + 16 * i + 4 * lg) = pack4(v0, v1, v2, v3);
        }
        {
          const float v0 = a1[0] + bi.x, v1 = a1[1] + bi.y, v2 = a1[2] + bi.z, v3 = a1[3] + bi.w;
          ssk1 += v0 * v0 + v1 * v1 + v2 * v2 + v3 * v3;
          *(ushort4*)(bufB1 + n_mine * ROWP + 16 * i + 4 * lg) = pack4(v0, v1, v2, v3);
        }
#pragma unroll
        for (int kk = 0; kk < 4; ++kk) aw[kk] = nw[kk];
      }
    }
    ssq0 += __shfl_xor(ssq0, 16); ssq0 += __shfl_xor(ssq0, 32);
    ssq1 += __shfl_xor(ssq1, 16); ssq1 += __shfl_xor(ssq1, 32);
    ssk0 += __shfl_xor(ssk0, 16); ssk0 += __shfl_xor(ssk0, 32);
    ssk1 += __shfl_xor(ssk1, 16); ssk1 += __shfl_xor(ssk1, 32);
    if (l < 16) {
      tab0[0 + n_mine] = ssq0; tab0[128 + n_mine] = ssk0;
      tab1[0 + n_mine] = ssq1; tab1[128 + n_mine] = ssk1;
    }
    __syncthreads();   // B1: q,k complete + norm partials

    if (t < 256) {
      const int tb = t >> 7, tt = t & 127;
      float* T = tb ? tab1 : tab0;
      T[0 + tt] = 1.0f / fmaxf(sqrtf(T[0 + tt]), 1e-12f);                 // 1/|q|
      T[512 + 4 * tt + 0] = (1.0f / fmaxf(sqrtf(T[128 + tt]), 1e-12f)) * F_SCALING;
      T[512 + 4 * tt + 1] = T[1280 + tt];   // sw
      T[512 + 4 * tt + 2] = 0.0f;
      T[512 + 4 * tt + 3] = T[1536 + tt];   // rx
      T[1024 + 2 * tt + 0] = T[1664 + tt];  // ry
      T[1024 + 2 * tt + 1] = T[1792 + tt];  // rz
    }
    // hoist q fragments for both b's (own rows)
    bf16x8 qf0[4], qf1[4];
#pragma unroll
    for (int kk = 0; kk < 4; ++kk) {
      qf0[kk] = *(const bf16x8*)(bufA0 + n_mine * ROWP + 8 * lg + 32 * kk);
      qf1[kk] = *(const bf16x8*)(bufA1 + n_mine * ROWP + 8 * lg + 32 * kk);
    }
    __syncthreads();   // B2: qf hoisted; factor tables ready; bufA free

    // ---- v: tiles 16..23 -> bufA0/bufA1 (weights shared; NO prefetch:
    //      qf0/qf1 live here, prefetch would exceed the ~128-arch ceiling) ----
    float ssv0 = 0.f, ssv1 = 0.f;
#pragma unroll 1
    for (int i = 0; i < 8; ++i) {
      bf16x8 aw[4];
#pragma unroll
      for (int kk = 0; kk < 4; ++kk)
        aw[kk] = wt_frag<WS>(wtI, WinL, 256 + 16 * i + lc, 8 * lg + 32 * kk, 384);
      f32x4 a0 = {0, 0, 0, 0}, a1 = {0, 0, 0, 0};
#pragma unroll
      for (int kk = 0; kk < 4; ++kk) {
        a0 = MFMA(aw[kk], xf0[kk], a0);
        a1 = MFMA(aw[kk], xf1[kk], a1);
      }
      const float4 bi = *(const float4*)&binL[256 + 16 * i + 4 * lg];
      {
        const float v0 = a0[0] + bi.x, v1 = a0[1] + bi.y, v2 = a0[2] + bi.z, v3 = a0[3] + bi.w;
        ssv0 += v0 * v0 + v1 * v1 + v2 * v2 + v3 * v3;
        *(ushort4*)(bufA0 + n_mine * ROWP + 16 * i + 4 * lg) = pack4(v0, v1, v2, v3);
      }
      {
        const float v0 = a1[0] + bi.x, v1 = a1[1] + bi.y, v2 = a1[2] + bi.z, v3 = a1[3] + bi.w;
        ssv1 += v0 * v0 + v1 * v1 + v2 * v2 + v3 * v3;
        *(ushort4*)(bufA1 + n_mine * ROWP + 16 * i + 4 * lg) = pack4(v0, v1, v2, v3);
      }
    }
    ssv0 += __shfl_xor(ssv0, 16); ssv0 += __shfl_xor(ssv0, 32);
    ssv1 += __shfl_xor(ssv1, 16); ssv1 += __shfl_xor(ssv1, 32);
    if (l < 16) { tab0[256 + n_mine] = ssv0; tab1[256 + n_mine] = ssv1; }

    // ---- S + softmax, b0 then b1 (sequenced); EARLY bf16 PACK of P ----
    ushort4 p0[8], p1[8];
    {
      const float iqn = tab0[0 + n_mine];
      const float swn = tab0[1280 + n_mine];
      const float rxn = tab0[1536 + n_mine], ryn = tab0[1664 + n_mine], rzn = tab0[1792 + n_mine];
      float sum = 0.0f;
      f32x4 sacc[8];
#pragma unroll 2
      for (int mt = 0; mt < 8; ++mt) {
        bf16x8 kf[4];
#pragma unroll
        for (int kk = 0; kk < 4; ++kk)
          kf[kk] = *(const bf16x8*)(bufB0 + (16 * mt + lc) * ROWP + 8 * lg + 32 * kk);
        f32x4 a = {0, 0, 0, 0};
#pragma unroll
        for (int kk = 0; kk < 4; ++kk) a = MFMA(kf[kk], qf0[kk], a);
#pragma unroll
        for (int r2 = 0; r2 < 4; ++r2) {
          const int m = 16 * mt + 4 * lg + r2;
          const float4 a4 = *(const float4*)&tab0[512 + 4 * m];
          const float2 b2 = *(const float2*)&tab0[1024 + 2 * m];
          const float sws = swn * a4.y;
          const float e = __expf((a[r2] * iqn * a4.x + F_SHIFT) * sws - F_SHIFT);
          sum += e;
          a[r2] = e * sws * (rxn * a4.w + ryn * b2.x + rzn * b2.y);
        }
        sacc[mt] = a;
      }
      sum += __shfl_xor(sum, 16); sum += __shfl_xor(sum, 32);
      const float fac = tab0[1408 + n_mine] / sum;
#pragma unroll
      for (int mt = 0; mt < 8; ++mt)
        p0[mt] = pack4(sacc[mt][0] * fac, sacc[mt][1] * fac, sacc[mt][2] * fac, sacc[mt][3] * fac);
    }
    {
      const float iqn = tab1[0 + n_mine];
      const float swn = tab1[1280 + n_mine];
      const float rxn = tab1[1536 + n_mine], ryn = tab1[1664 + n_mine], rzn = tab1[1792 + n_mine];
      float sum = 0.0f;
      f32x4 sacc[8];
#pragma unroll 2
      for (int mt = 0; mt < 8; ++mt) {
        bf16x8 kf[4];
#pragma unroll
        for (int kk = 0; kk < 4; ++kk)
          kf[kk] = *(const bf16x8*)(bufB1 + (16 * mt + lc) * ROWP + 8 * lg + 32 * kk);
        f32x4 a = {0, 0, 0, 0};
#pragma unroll
        for (int kk = 0; kk < 4; ++kk) a = MFMA(kf[kk], qf1[kk], a);
#pragma unroll
        for (int r2 = 0; r2 < 4; ++r2) {
          const int m = 16 * mt + 4 * lg + r2;
          const float4 a4 = *(const float4*)&tab1[512 + 4 * m];
          const float2 b2 = *(const float2*)&tab1[1024 + 2 * m];
          const float sws = swn * a4.y;
          const float e = __expf((a[r2] * iqn * a4.x + F_SHIFT) * sws - F_SHIFT);
          sum += e;
          a[r2] = e * sws * (rxn * a4.w + ryn * b2.x + rzn * b2.y);
        }
        sacc[mt] = a;
      }
      sum += __shfl_xor(sum, 16); sum += __shfl_xor(sum, 32);
      const float fac = tab1[1408 + n_mine] / sum;
#pragma unroll
      for (int mt = 0; mt < 8; ++mt)
        p1[mt] = pack4(sacc[mt][0] * fac, sacc[mt][1] * fac, sacc[mt][2] * fac, sacc[mt][3] * fac);
    }
    __syncthreads();   // B3: v writes + pV done; all S reads of bufB done

    if (t < 256) {
      const int tb = t >> 7, tt = t & 127;
      float* T = tb ? tab1 : tab0;
      T[384 + tt] = 1.0f / fmaxf(sqrtf(T[256 + tt]), 1e-12f);   // 1/|v|
    }
    // store pre-packed P -> bufB (own rows)
#pragma unroll
    for (int mt = 0; mt < 8; ++mt) {
      *(ushort4*)(bufB0 + n_mine * ROWP + 16 * mt + 4 * lg) = p0[mt];
      *(ushort4*)(bufB1 + n_mine * ROWP + 16 * mt + 4 * lg) = p1[mt];
    }
    // hoist v fragments (own rows)
    bf16x8 vf0[4], vf1[4];
#pragma unroll
    for (int kk = 0; kk < 4; ++kk) {
      vf0[kk] = *(const bf16x8*)(bufA0 + n_mine * ROWP + 8 * lg + 32 * kk);
      vf1[kk] = *(const bf16x8*)(bufA1 + n_mine * ROWP + 8 * lg + 32 * kk);
    }
    __syncthreads();   // B4: P stored, vf hoisted, sIV ready; bufA free

    // ---- VW^T = (v @ W_out)^T * iv -> bufA (weights shared; PREFETCHED) ----
    {
      const float4 iv0 = *(const float4*)&tab0[384 + 16 * w + 4 * lg];
      const float4 iv1 = *(const float4*)&tab1[384 + 16 * w + 4 * lg];
      bf16x8 bw[4], nw[4];
#pragma unroll
      for (int kk = 0; kk < 4; ++kk)
        bw[kk] = wt_frag<WS>(wtO, WoutL, lc, 8 * lg + 32 * kk, 128);
#pragma unroll 1
      for (int i = 0; i < 8; ++i) {
        if (i < 7) {
#pragma unroll
          for (int kk = 0; kk < 4; ++kk)
            nw[kk] = wt_frag<WS>(wtO, WoutL, 16 * (i + 1) + lc, 8 * lg + 32 * kk, 128);
        }
        f32x4 a0 = {0, 0, 0, 0}, a1 = {0, 0, 0, 0};
#pragma unroll
        for (int kk = 0; kk < 4; ++kk) {
          a0 = MFMA(vf0[kk], bw[kk], a0);
          a1 = MFMA(vf1[kk], bw[kk], a1);
        }
        *(ushort4*)(bufA0 + (16 * i + lc) * ROWP + 16 * w + 4 * lg) =
            pack4(a0[0] * iv0.x, a0[1] * iv0.y, a0[2] * iv0.z, a0[3] * iv0.w);
        *(ushort4*)(bufA1 + (16 * i + lc) * ROWP + 16 * w + 4 * lg) =
            pack4(a1[0] * iv1.x, a1[1] * iv1.y, a1[2] * iv1.z, a1[3] * iv1.w);
#pragma unroll
        for (int kk = 0; kk < 4; ++kk) bw[kk] = nw[kk];
      }
    }
    __syncthreads();   // B5: VW^T complete

    // hoist P fragments (own rows; bufB untouched since P store)
    bf16x8 pf0[4], pf1[4];
#pragma unroll
    for (int kk = 0; kk < 4; ++kk) {
      pf0[kk] = *(const bf16x8*)(bufB0 + n_mine * ROWP + 8 * lg + 32 * kk);
      pf1[kk] = *(const bf16x8*)(bufB1 + n_mine * ROWP + 8 * lg + 32 * kk);
    }

    // ---- PV + LN epilogue, b0 then b1 (SEQUENCED) ----
    float bo8[8], g8[8], be8[8];
#pragma unroll
    for (int ct = 0; ct < 8; ++ct) {
      const int e = 16 * ct + lc;
      bo8[ct] = boutL[e]; g8[ct] = lngL[e]; be8[ct] = lnbL[e];
    }
#pragma unroll 1
    for (int which = 0; which < 2; ++which) {
      const ushort_t* bufA = which ? bufA1 : bufA0;
      const float* xsrc = which ? xsrc1 : xsrc0;
      float* xo = xout + (which ? bb1 : bb0);
      f32x4 oacc[8];
#pragma unroll 2
      for (int i = 0; i < 8; ++i) {
        bf16x8 bf[4];
#pragma unroll
        for (int kk = 0; kk < 4; ++kk)
          bf[kk] = *(const bf16x8*)(bufA + (16 * i + lc) * ROWP + 8 * lg + 32 * kk);
        f32x4 a = {0, 0, 0, 0};
        if (which == 0) {
#pragma unroll
          for (int kk = 0; kk < 4; ++kk) a = MFMA(pf0[kk], bf[kk], a);
        } else {
#pragma unroll
          for (int kk = 0; kk < 4; ++kk) a = MFMA(pf1[kk], bf[kk], a);
        }
        oacc[i] = a;
      }
#pragma unroll
      for (int r2 = 0; r2 < 4; ++r2) {
        const int n = 16 * w + 4 * lg + r2;
        const float* xr = xsrc + (size_t)n * 128;
        float vals[8];
        float s1 = 0.0f, s2 = 0.0f;
#pragma unroll
        for (int ct = 0; ct < 8; ++ct) {
          const float v = oacc[ct][r2] + bo8[ct] + xr[16 * ct + lc];
          vals[ct] = v; s1 += v; s2 += v * v;
        }
        s1 += __shfl_xor(s1, 1); s1 += __shfl_xor(s1, 2);
        s1 += __shfl_xor(s1, 4); s1 += __shfl_xor(s1, 8);
        s2 += __shfl_xor(s2, 1); s2 += __shfl_xor(s2, 2);
        s2 += __shfl_xor(s2, 4); s2 += __shfl_xor(s2, 8);
        const float mu = s1 * (1.0f / 128.0f);
        const float rs = rsqrtf(s2 * (1.0f / 128.0f) - mu * mu + F_LNEPS);
        float* orow = xo + (size_t)n * 128;
#pragma unroll
        for (int ct = 0; ct < 8; ++ct)
          orow[16 * ct + lc] = (vals[ct] - mu) * rs * g8[ct] + be8[ct];
      }
    }
    __syncthreads();   // B6: layer boundary (buffers reused; xout -> next xsrc)
  }
}

extern "C" void kernel_launch(void* const* d_in, const int* in_sizes, int n_in,
                              void* d_out, int out_size, void* d_ws, size_t ws_size,
                              hipStream_t stream) {
  const float* G    = (const float*)d_in[0];
  const int*   msk  = (const int*)d_in[1];
  const float* r3   = (const float*)d_in[2];
  const float* swg  = (const float*)d_in[3];
  const float* Win  = (const float*)d_in[4];
  const float* bin  = (const float*)d_in[5];
  const float* Wout = (const float*)d_in[6];
  const float* bout = (const float*)d_in[7];
  const float* lng  = (const float*)d_in[8];
  const float* lnb  = (const float*)d_in[9];
  float* xout = (float*)d_out;

  const int B = in_sizes[0] / (128 * 128);
  const int nblk = B / 2;
  const bool ws_ok = ws_size >= (WTI_ELEMS + WTO_ELEMS) * sizeof(ushort_t);
  ushort_t* wtI = (ushort_t*)d_ws;
  ushort_t* wtO = wtI + WTI_ELEMS;

  if (ws_ok) {
    prep_weights<<<dim3(384), dim3(256), 0, stream>>>(Win, Wout, wtI, wtO);
    hipFuncSetAttribute(reinterpret_cast<const void*>(ngatt_dual<true>),
                        hipFuncAttributeMaxDynamicSharedMemorySize, LDS_BYTES);
    ngatt_dual<true><<<dim3(nblk), dim3(512), LDS_BYTES, stream>>>(
        G, msk, r3, swg, Win, bin, Wout, bout, lng, lnb, wtI, wtO, xout);
  } else {
    hipFuncSetAttribute(reinterpret_cast<const void*>(ngatt_dual<false>),
                        hipFuncAttributeMaxDynamicSharedMemorySize, LDS_BYTES);
    ngatt_dual<false><<<dim3(nblk), dim3(512), LDS_BYTES, stream>>>(
        G, msk, r3, swg, Win, bin, Wout, bout, lng, lnb, nullptr, nullptr, xout);
  }
}

// Round 13
// 1680.017 us; speedup vs baseline: 1.5424x; 1.1948x over previous
//
#include <hip/hip_runtime.h>
#include <hip/hip_bf16.h>
#include <math.h>

// NeighborGatedAttention, bf16-MFMA, DUAL-b (R9 structure, register-diet).
// L=2, B=8192, NNEI=128, EMB=HID=128. One block (512 thr = 8 waves), TWO b's.
// R10/11/12 proved ANY prefetch spills (+0.4..1.7GB scratch traffic) and
// loses; weight-load latency is only ~4% of block time. So: NO prefetch.
// vs R9 (1735us, the best): only register-reducing/neutral edits:
//  (1) early P pack (sacc fp32 dies before S_b1),
//  (2) pf hoist inside PV which-loop (not live through VW),
//  (3) residual loads hoisted before PV MFMAs (one overlapped HBM wait
//      instead of 4 serial ~900cy waits per b-layer),
//  (4) s_setprio(1/0) around S/PV MFMA chains.
// LDS 154.6KB, 1 block/CU, 2 waves/SIMD.
// All GEMMs v_mfma_f32_16x16x32_bf16; l2-norms from fp32 accs; softmax/LN fp32.

typedef __attribute__((ext_vector_type(8))) short bf16x8; // 8 bf16 = 4 VGPR
typedef __attribute__((ext_vector_type(4))) float f32x4;
typedef unsigned short ushort_t;

constexpr float F_SHIFT   = 20.0f;
constexpr float F_SCALING = 0.08838834764831845f; // 128^-0.5
constexpr float F_LNEPS   = 1e-5f;

constexpr int ROWP = 136;                 // ushort row pitch (272B)
constexpr int BUF_US = 128 * ROWP;        // 17408 ushorts per buffer
constexpr size_t WTI_ELEMS = 2 * 384 * 128;
constexpr size_t WTO_ELEMS = 2 * 128 * 128;
constexpr int TAB_F = 1920;               // per-b table floats
constexpr int LDS_BYTES = 4 * BUF_US * 2 + 2 * TAB_F * 4; // 154624

#define MFMA(a, b, c) __builtin_amdgcn_mfma_f32_16x16x32_bf16(a, b, c, 0, 0, 0)

__device__ __forceinline__ ushort_t f2bf(float f) {
  __hip_bfloat16 h = __float2bfloat16(f);
  return *reinterpret_cast<ushort_t*>(&h);
}
__device__ __forceinline__ ushort4 pack4(float a, float b, float c, float d) {
  return make_ushort4(f2bf(a), f2bf(b), f2bf(c), f2bf(d));
}

// A/B fragment from pre-transposed bf16 weights (WS) or fp32 gather fallback.
template <bool WS>
__device__ __forceinline__ bf16x8 wt_frag(const ushort_t* __restrict__ wt,
                                          const float* __restrict__ W,
                                          int r, int c, int ldW) {
  if constexpr (WS) {
    return *(const bf16x8*)(wt + r * 128 + c);
  } else {
    bf16x8 f;
#pragma unroll
    for (int j = 0; j < 8; ++j) f[j] = (short)f2bf(W[(size_t)(c + j) * ldW + r]);
    return f;
  }
}

__global__ void prep_weights(const float* __restrict__ Win, const float* __restrict__ Wout,
                             ushort_t* __restrict__ wtI, ushort_t* __restrict__ wtO) {
  const int i = blockIdx.x * 256 + threadIdx.x;
  if (i < (int)WTI_ELEMS) {   // wtI[l][h][e] = bf16(Win[l][e][h])
    const int l = i / (384 * 128), r = i % (384 * 128), h = r >> 7, e = r & 127;
    wtI[i] = f2bf(Win[l * (128 * 384) + e * 384 + h]);
  }
  if (i < (int)WTO_ELEMS) {   // wtO[l][e][h] = bf16(Wout[l][h][e])
    const int l = i >> 14, r = i & 16383, e = r >> 7, h = r & 127;
    wtO[i] = f2bf(Wout[(l << 14) + h * 128 + e]);
  }
}

__device__ __forceinline__ bf16x8 load_xf(const float* xr) {
  const float4 a = *(const float4*)xr;
  const float4 c = *(const float4*)(xr + 4);
  bf16x8 f;
  f[0] = (short)f2bf(a.x); f[1] = (short)f2bf(a.y);
  f[2] = (short)f2bf(a.z); f[3] = (short)f2bf(a.w);
  f[4] = (short)f2bf(c.x); f[5] = (short)f2bf(c.y);
  f[6] = (short)f2bf(c.z); f[7] = (short)f2bf(c.w);
  return f;
}

template <bool WS>
__global__ __launch_bounds__(512, 2)
void ngatt_dual(const float* __restrict__ G, const int* __restrict__ nmask,
                const float* __restrict__ r3, const float* __restrict__ swg,
                const float* __restrict__ Win, const float* __restrict__ bin,
                const float* __restrict__ Wout, const float* __restrict__ bout,
                const float* __restrict__ lng, const float* __restrict__ lnb,
                const ushort_t* __restrict__ wtin, const ushort_t* __restrict__ wtout,
                float* __restrict__ xout) {
  extern __shared__ char smem[];
  ushort_t* bufA0 = (ushort_t*)smem;           // b0: q -> v -> VW^T
  ushort_t* bufB0 = bufA0 + BUF_US;            // b0: k -> P
  ushort_t* bufA1 = bufB0 + BUF_US;            // b1: q -> v -> VW^T
  ushort_t* bufB1 = bufA1 + BUF_US;            // b1: k -> P
  float* tab0 = (float*)(bufB1 + BUF_US);
  float* tab1 = tab0 + TAB_F;
  // per-b table layout (float offsets):
  //   pQ 0, pK 128, pV 256, sIV 384, fA 512..1023, fB 1024..1279,
  //   sSW 1280, sMK 1408, sRX 1536, sRY 1664, sRZ 1792

  const int bid = blockIdx.x, t = threadIdx.x;
  const int w = t >> 6, l = t & 63, lc = l & 15, lg = l >> 4;
  const int b0 = 2 * bid, b1 = b0 + 1;
  const size_t bb0 = (size_t)b0 * (128 * 128);
  const size_t bb1 = (size_t)b1 * (128 * 128);
  const int n_mine = 16 * w + lc;

  if (t < 256) {
    const int tb = t >> 7, tt = t & 127;
    float* T = tb ? tab1 : tab0;
    const size_t gi = (size_t)(b0 + tb) * 128 + tt;
    T[1280 + tt] = swg[gi];
    T[1408 + tt] = nmask[gi] ? 1.0f : 0.0f;
    T[1536 + tt] = r3[gi * 3 + 0];
    T[1664 + tt] = r3[gi * 3 + 1];
    T[1792 + tt] = r3[gi * 3 + 2];
  }
  __syncthreads();

  for (int layer = 0; layer < 2; ++layer) {
    const float* xsrc0 = layer ? (xout + bb0) : (G + bb0);
    const float* xsrc1 = layer ? (xout + bb1) : (G + bb1);
    const ushort_t* wtI = wtin + (size_t)layer * 384 * 128;
    const ushort_t* wtO = wtout + (size_t)layer * 128 * 128;
    const float* WinL  = Win  + (size_t)layer * 128 * 384;
    const float* WoutL = Wout + (size_t)layer * 128 * 128;
    const float* binL  = bin  + layer * 384;
    const float* boutL = bout + layer * 128;
    const float* lngL  = lng  + layer * 128;
    const float* lnbL  = lnb  + layer * 128;

    // ---- hoist x B-fragments for both b's (col n_mine) ----
    bf16x8 xf0[4], xf1[4];
#pragma unroll
    for (int kk = 0; kk < 4; ++kk) {
      xf0[kk] = load_xf(xsrc0 + (size_t)n_mine * 128 + 8 * lg + 32 * kk);
      xf1[kk] = load_xf(xsrc1 + (size_t)n_mine * 128 + 8 * lg + 32 * kk);
    }

    // ---- q: tiles 0..7 -> bufA0/bufA1 (weights shared; NO prefetch) ----
    float ssq0 = 0.f, ssq1 = 0.f, ssk0 = 0.f, ssk1 = 0.f;
#pragma unroll 2
    for (int i = 0; i < 8; ++i) {
      bf16x8 aw[4];
#pragma unroll
      for (int kk = 0; kk < 4; ++kk)
        aw[kk] = wt_frag<WS>(wtI, WinL, 16 * i + lc, 8 * lg + 32 * kk, 384);
      f32x4 a0 = {0, 0, 0, 0}, a1 = {0, 0, 0, 0};
#pragma unroll
      for (int kk = 0; kk < 4; ++kk) {
        a0 = MFMA(aw[kk], xf0[kk], a0);
        a1 = MFMA(aw[kk], xf1[kk], a1);
      }
      const float4 bi = *(const float4*)&binL[16 * i + 4 * lg];
      {
        const float v0 = a0[0] + bi.x, v1 = a0[1] + bi.y, v2 = a0[2] + bi.z, v3 = a0[3] + bi.w;
        ssq0 += v0 * v0 + v1 * v1 + v2 * v2 + v3 * v3;
        *(ushort4*)(bufA0 + n_mine * ROWP + 16 * i + 4 * lg) = pack4(v0, v1, v2, v3);
      }
      {
        const float v0 = a1[0] + bi.x, v1 = a1[1] + bi.y, v2 = a1[2] + bi.z, v3 = a1[3] + bi.w;
        ssq1 += v0 * v0 + v1 * v1 + v2 * v2 + v3 * v3;
        *(ushort4*)(bufA1 + n_mine * ROWP + 16 * i + 4 * lg) = pack4(v0, v1, v2, v3);
      }
    }
    // ---- k: tiles 8..15 -> bufB0/bufB1 ----
#pragma unroll 2
    for (int i = 0; i < 8; ++i) {
      bf16x8 aw[4];
#pragma unroll
      for (int kk = 0; kk < 4; ++kk)
        aw[kk] = wt_frag<WS>(wtI, WinL, 128 + 16 * i + lc, 8 * lg + 32 * kk, 384);
      f32x4 a0 = {0, 0, 0, 0}, a1 = {0, 0, 0, 0};
#pragma unroll
      for (int kk = 0; kk < 4; ++kk) {
        a0 = MFMA(aw[kk], xf0[kk], a0);
        a1 = MFMA(aw[kk], xf1[kk], a1);
      }
      const float4 bi = *(const float4*)&binL[128 + 16 * i + 4 * lg];
      {
        const float v0 = a0[0] + bi.x, v1 = a0[1] + bi.y, v2 = a0[2] + bi.z, v3 = a0[3] + bi.w;
        ssk0 += v0 * v0 + v1 * v1 + v2 * v2 + v3 * v3;
        *(ushort4*)(bufB0 + n_mine * ROWP + 16 * i + 4 * lg) = pack4(v0, v1, v2, v3);
      }
      {
        const float v0 = a1[0] + bi.x, v1 = a1[1] + bi.y, v2 = a1[2] + bi.z, v3 = a1[3] + bi.w;
        ssk1 += v0 * v0 + v1 * v1 + v2 * v2 + v3 * v3;
        *(ushort4*)(bufB1 + n_mine * ROWP + 16 * i + 4 * lg) = pack4(v0, v1, v2, v3);
      }
    }
    ssq0 += __shfl_xor(ssq0, 16); ssq0 += __shfl_xor(ssq0, 32);
    ssq1 += __shfl_xor(ssq1, 16); ssq1 += __shfl_xor(ssq1, 32);
    ssk0 += __shfl_xor(ssk0, 16); ssk0 += __shfl_xor(ssk0, 32);
    ssk1 += __shfl_xor(ssk1, 16); ssk1 += __shfl_xor(ssk1, 32);
    if (l < 16) {
      tab0[0 + n_mine] = ssq0; tab0[128 + n_mine] = ssk0;
      tab1[0 + n_mine] = ssq1; tab1[128 + n_mine] = ssk1;
    }
    __syncthreads();   // B1: q,k complete + norm partials

    if (t < 256) {
      const int tb = t >> 7, tt = t & 127;
      float* T = tb ? tab1 : tab0;
      T[0 + tt] = 1.0f / fmaxf(sqrtf(T[0 + tt]), 1e-12f);                 // 1/|q|
      T[512 + 4 * tt + 0] = (1.0f / fmaxf(sqrtf(T[128 + tt]), 1e-12f)) * F_SCALING;
      T[512 + 4 * tt + 1] = T[1280 + tt];   // sw
      T[512 + 4 * tt + 2] = 0.0f;
      T[512 + 4 * tt + 3] = T[1536 + tt];   // rx
      T[1024 + 2 * tt + 0] = T[1664 + tt];  // ry
      T[1024 + 2 * tt + 1] = T[1792 + tt];  // rz
    }
    // hoist q fragments for both b's (own rows)
    bf16x8 qf0[4], qf1[4];
#pragma unroll
    for (int kk = 0; kk < 4; ++kk) {
      qf0[kk] = *(const bf16x8*)(bufA0 + n_mine * ROWP + 8 * lg + 32 * kk);
      qf1[kk] = *(const bf16x8*)(bufA1 + n_mine * ROWP + 8 * lg + 32 * kk);
    }
    __syncthreads();   // B2: qf hoisted; factor tables ready; bufA free

    // ---- v: tiles 16..23 -> bufA0/bufA1 (weights shared; NO prefetch) ----
    float ssv0 = 0.f, ssv1 = 0.f;
#pragma unroll 2
    for (int i = 0; i < 8; ++i) {
      bf16x8 aw[4];
#pragma unroll
      for (int kk = 0; kk < 4; ++kk)
        aw[kk] = wt_frag<WS>(wtI, WinL, 256 + 16 * i + lc, 8 * lg + 32 * kk, 384);
      f32x4 a0 = {0, 0, 0, 0}, a1 = {0, 0, 0, 0};
#pragma unroll
      for (int kk = 0; kk < 4; ++kk) {
        a0 = MFMA(aw[kk], xf0[kk], a0);
        a1 = MFMA(aw[kk], xf1[kk], a1);
      }
      const float4 bi = *(const float4*)&binL[256 + 16 * i + 4 * lg];
      {
        const float v0 = a0[0] + bi.x, v1 = a0[1] + bi.y, v2 = a0[2] + bi.z, v3 = a0[3] + bi.w;
        ssv0 += v0 * v0 + v1 * v1 + v2 * v2 + v3 * v3;
        *(ushort4*)(bufA0 + n_mine * ROWP + 16 * i + 4 * lg) = pack4(v0, v1, v2, v3);
      }
      {
        const float v0 = a1[0] + bi.x, v1 = a1[1] + bi.y, v2 = a1[2] + bi.z, v3 = a1[3] + bi.w;
        ssv1 += v0 * v0 + v1 * v1 + v2 * v2 + v3 * v3;
        *(ushort4*)(bufA1 + n_mine * ROWP + 16 * i + 4 * lg) = pack4(v0, v1, v2, v3);
      }
    }
    ssv0 += __shfl_xor(ssv0, 16); ssv0 += __shfl_xor(ssv0, 32);
    ssv1 += __shfl_xor(ssv1, 16); ssv1 += __shfl_xor(ssv1, 32);
    if (l < 16) { tab0[256 + n_mine] = ssv0; tab1[256 + n_mine] = ssv1; }

    // ---- S + softmax, b0 then b1 (sequenced); EARLY bf16 pack of P ----
    ushort4 p0[8], p1[8];
    {
      const float iqn = tab0[0 + n_mine];
      const float swn = tab0[1280 + n_mine];
      const float rxn = tab0[1536 + n_mine], ryn = tab0[1664 + n_mine], rzn = tab0[1792 + n_mine];
      float sum = 0.0f;
      f32x4 sacc[8];
#pragma unroll 2
      for (int mt = 0; mt < 8; ++mt) {
        bf16x8 kf[4];
#pragma unroll
        for (int kk = 0; kk < 4; ++kk)
          kf[kk] = *(const bf16x8*)(bufB0 + (16 * mt + lc) * ROWP + 8 * lg + 32 * kk);
        __builtin_amdgcn_s_setprio(1);
        f32x4 a = {0, 0, 0, 0};
#pragma unroll
        for (int kk = 0; kk < 4; ++kk) a = MFMA(kf[kk], qf0[kk], a);
        __builtin_amdgcn_s_setprio(0);
#pragma unroll
        for (int r2 = 0; r2 < 4; ++r2) {
          const int m = 16 * mt + 4 * lg + r2;
          const float4 a4 = *(const float4*)&tab0[512 + 4 * m];
          const float2 b2 = *(const float2*)&tab0[1024 + 2 * m];
          const float sws = swn * a4.y;
          const float e = __expf((a[r2] * iqn * a4.x + F_SHIFT) * sws - F_SHIFT);
          sum += e;
          a[r2] = e * sws * (rxn * a4.w + ryn * b2.x + rzn * b2.y);
        }
        sacc[mt] = a;
      }
      sum += __shfl_xor(sum, 16); sum += __shfl_xor(sum, 32);
      const float fac = tab0[1408 + n_mine] / sum;
#pragma unroll
      for (int mt = 0; mt < 8; ++mt)
        p0[mt] = pack4(sacc[mt][0] * fac, sacc[mt][1] * fac, sacc[mt][2] * fac, sacc[mt][3] * fac);
    }
    {
      const float iqn = tab1[0 + n_mine];
      const float swn = tab1[1280 + n_mine];
      const float rxn = tab1[1536 + n_mine], ryn = tab1[1664 + n_mine], rzn = tab1[1792 + n_mine];
      float sum = 0.0f;
      f32x4 sacc[8];
#pragma unroll 2
      for (int mt = 0; mt < 8; ++mt) {
        bf16x8 kf[4];
#pragma unroll
        for (int kk = 0; kk < 4; ++kk)
          kf[kk] = *(const bf16x8*)(bufB1 + (16 * mt + lc) * ROWP + 8 * lg + 32 * kk);
        __builtin_amdgcn_s_setprio(1);
        f32x4 a = {0, 0, 0, 0};
#pragma unroll
        for (int kk = 0; kk < 4; ++kk) a = MFMA(kf[kk], qf1[kk], a);
        __builtin_amdgcn_s_setprio(0);
#pragma unroll
        for (int r2 = 0; r2 < 4; ++r2) {
          const int m = 16 * mt + 4 * lg + r2;
          const float4 a4 = *(const float4*)&tab1[512 + 4 * m];
          const float2 b2 = *(const float2*)&tab1[1024 + 2 * m];
          const float sws = swn * a4.y;
          const float e = __expf((a[r2] * iqn * a4.x + F_SHIFT) * sws - F_SHIFT);
          sum += e;
          a[r2] = e * sws * (rxn * a4.w + ryn * b2.x + rzn * b2.y);
        }
        sacc[mt] = a;
      }
      sum += __shfl_xor(sum, 16); sum += __shfl_xor(sum, 32);
      const float fac = tab1[1408 + n_mine] / sum;
#pragma unroll
      for (int mt = 0; mt < 8; ++mt)
        p1[mt] = pack4(sacc[mt][0] * fac, sacc[mt][1] * fac, sacc[mt][2] * fac, sacc[mt][3] * fac);
    }
    __syncthreads();   // B3: v writes + pV done; all S reads of bufB done

    if (t < 256) {
      const int tb = t >> 7, tt = t & 127;
      float* T = tb ? tab1 : tab0;
      T[384 + tt] = 1.0f / fmaxf(sqrtf(T[256 + tt]), 1e-12f);   // 1/|v|
    }
    // store pre-packed P -> bufB (own rows)
#pragma unroll
    for (int mt = 0; mt < 8; ++mt) {
      *(ushort4*)(bufB0 + n_mine * ROWP + 16 * mt + 4 * lg) = p0[mt];
      *(ushort4*)(bufB1 + n_mine * ROWP + 16 * mt + 4 * lg) = p1[mt];
    }
    // hoist v fragments (own rows)
    bf16x8 vf0[4], vf1[4];
#pragma unroll
    for (int kk = 0; kk < 4; ++kk) {
      vf0[kk] = *(const bf16x8*)(bufA0 + n_mine * ROWP + 8 * lg + 32 * kk);
      vf1[kk] = *(const bf16x8*)(bufA1 + n_mine * ROWP + 8 * lg + 32 * kk);
    }
    __syncthreads();   // B4: P stored, vf hoisted, sIV ready; bufA free

    // ---- VW^T = (v @ W_out)^T * iv -> bufA (weights shared; NO prefetch) ----
    {
      const float4 iv0 = *(const float4*)&tab0[384 + 16 * w + 4 * lg];
      const float4 iv1 = *(const float4*)&tab1[384 + 16 * w + 4 * lg];
#pragma unroll 2
      for (int i = 0; i < 8; ++i) {
        bf16x8 bw[4];
#pragma unroll
        for (int kk = 0; kk < 4; ++kk)
          bw[kk] = wt_frag<WS>(wtO, WoutL, 16 * i + lc, 8 * lg + 32 * kk, 128);
        f32x4 a0 = {0, 0, 0, 0}, a1 = {0, 0, 0, 0};
#pragma unroll
        for (int kk = 0; kk < 4; ++kk) {
          a0 = MFMA(vf0[kk], bw[kk], a0);
          a1 = MFMA(vf1[kk], bw[kk], a1);
        }
        *(ushort4*)(bufA0 + (16 * i + lc) * ROWP + 16 * w + 4 * lg) =
            pack4(a0[0] * iv0.x, a0[1] * iv0.y, a0[2] * iv0.z, a0[3] * iv0.w);
        *(ushort4*)(bufA1 + (16 * i + lc) * ROWP + 16 * w + 4 * lg) =
            pack4(a1[0] * iv1.x, a1[1] * iv1.y, a1[2] * iv1.z, a1[3] * iv1.w);
      }
    }
    __syncthreads();   // B5: VW^T complete

    // ---- PV + LN epilogue, b0 then b1 (sequenced).
    //      pf hoisted per-which (not live through VW); residual loads
    //      hoisted BEFORE the MFMA loop so HBM latency hides under PV. ----
    float bo8[8], g8[8], be8[8];
#pragma unroll
    for (int ct = 0; ct < 8; ++ct) {
      const int e = 16 * ct + lc;
      bo8[ct] = boutL[e]; g8[ct] = lngL[e]; be8[ct] = lnbL[e];
    }
#pragma unroll 1
    for (int which = 0; which < 2; ++which) {
      const ushort_t* bufA = which ? bufA1 : bufA0;
      const ushort_t* bufB = which ? bufB1 : bufB0;
      const float* xsrc = which ? xsrc1 : xsrc0;
      float* xo = xout + (which ? bb1 : bb0);

      // residual hoist: 32 floats, issued early (independent HBM loads)
      float xr8[4][8];
#pragma unroll
      for (int r2 = 0; r2 < 4; ++r2) {
        const float* xr = xsrc + (size_t)(16 * w + 4 * lg + r2) * 128;
#pragma unroll
        for (int ct = 0; ct < 8; ++ct) xr8[r2][ct] = xr[16 * ct + lc];
      }

      // pf hoist (own rows; bufB untouched since P store)
      bf16x8 pf[4];
#pragma unroll
      for (int kk = 0; kk < 4; ++kk)
        pf[kk] = *(const bf16x8*)(bufB + n_mine * ROWP + 8 * lg + 32 * kk);

      f32x4 oacc[8];
#pragma unroll 2
      for (int i = 0; i < 8; ++i) {
        bf16x8 bf[4];
#pragma unroll
        for (int kk = 0; kk < 4; ++kk)
          bf[kk] = *(const bf16x8*)(bufA + (16 * i + lc) * ROWP + 8 * lg + 32 * kk);
        __builtin_amdgcn_s_setprio(1);
        f32x4 a = {0, 0, 0, 0};
#pragma unroll
        for (int kk = 0; kk < 4; ++kk) a = MFMA(pf[kk], bf[kk], a);
        __builtin_amdgcn_s_setprio(0);
        oacc[i] = a;
      }
#pragma unroll
      for (int r2 = 0; r2 < 4; ++r2) {
        const int n = 16 * w + 4 * lg + r2;
        float vals[8];
        float s1 = 0.0f, s2 = 0.0f;
#pragma unroll
        for (int ct = 0; ct < 8; ++ct) {
          const float v = oacc[ct][r2] + bo8[ct] + xr8[r2][ct];
          vals[ct] = v; s1 += v; s2 += v * v;
        }
        s1 += __shfl_xor(s1, 1); s1 += __shfl_xor(s1, 2);
        s1 += __shfl_xor(s1, 4); s1 += __shfl_xor(s1, 8);
        s2 += __shfl_xor(s2, 1); s2 += __shfl_xor(s2, 2);
        s2 += __shfl_xor(s2, 4); s2 += __shfl_xor(s2, 8);
        const float mu = s1 * (1.0f / 128.0f);
        const float rs = rsqrtf(s2 * (1.0f / 128.0f) - mu * mu + F_LNEPS);
        float* orow = xo + (size_t)n * 128;
#pragma unroll
        for (int ct = 0; ct < 8; ++ct)
          orow[16 * ct + lc] = (vals[ct] - mu) * rs * g8[ct] + be8[ct];
      }
    }
    __syncthreads();   // B6: layer boundary (buffers reused; xout -> next xsrc)
  }
}

extern "C" void kernel_launch(void* const* d_in, const int* in_sizes, int n_in,
                              void* d_out, int out_size, void* d_ws, size_t ws_size,
                              hipStream_t stream) {
  const float* G    = (const float*)d_in[0];
  const int*   msk  = (const int*)d_in[1];
  const float* r3   = (const float*)d_in[2];
  const float* swg  = (const float*)d_in[3];
  const float* Win  = (const float*)d_in[4];
  const float* bin  = (const float*)d_in[5];
  const float* Wout = (const float*)d_in[6];
  const float* bout = (const float*)d_in[7];
  const float* lng  = (const float*)d_in[8];
  const float* lnb  = (const float*)d_in[9];
  float* xout = (float*)d_out;

  const int B = in_sizes[0] / (128 * 128);
  const int nblk = B / 2;
  const bool ws_ok = ws_size >= (WTI_ELEMS + WTO_ELEMS) * sizeof(ushort_t);
  ushort_t* wtI = (ushort_t*)d_ws;
  ushort_t* wtO = wtI + WTI_ELEMS;

  if (ws_ok) {
    prep_weights<<<dim3(384), dim3(256), 0, stream>>>(Win, Wout, wtI, wtO);
    hipFuncSetAttribute(reinterpret_cast<const void*>(ngatt_dual<true>),
                        hipFuncAttributeMaxDynamicSharedMemorySize, LDS_BYTES);
    ngatt_dual<true><<<dim3(nblk), dim3(512), LDS_BYTES, stream>>>(
        G, msk, r3, swg, Win, bin, Wout, bout, lng, lnb, wtI, wtO, xout);
  } else {
    hipFuncSetAttribute(reinterpret_cast<const void*>(ngatt_dual<false>),
                        hipFuncAttributeMaxDynamicSharedMemorySize, LDS_BYTES);
    ngatt_dual<false><<<dim3(nblk), dim3(512), LDS_BYTES, stream>>>(
        G, msk, r3, swg, Win, bin, Wout, bout, lng, lnb, nullptr, nullptr, xout);
  }
}